// Round 2
// baseline (615.442 us; speedup 1.0000x reference)
//
#include <hip/hip_runtime.h>
#include <cstdint>

typedef unsigned short u16;
typedef __attribute__((ext_vector_type(8))) short bf16x8;
typedef __attribute__((ext_vector_type(4))) float f32x4;

#define DIM   1024
#define BATCH 4
#define SEQ   4096
#define E3    3072
#define MTOT  (BATCH*SEQ)   // 16384

// ---------- bf16 helpers (RNE) ----------
__device__ __forceinline__ u16 f2bf(float x) {
    union { float f; unsigned u; } v; v.f = x;
    unsigned r = v.u + 0x7FFFu + ((v.u >> 16) & 1u);
    return (u16)(r >> 16);
}

// ---------- async global->LDS 16B ----------
__device__ __forceinline__ void gl16(const void* g, void* l) {
    __builtin_amdgcn_global_load_lds(
        (const __attribute__((address_space(1))) void*)g,
        (__attribute__((address_space(3))) void*)l, 16, 0, 0);
}

// ---------------------------------------------------------------------------
// GEMM mainloop: C[256x256] += A * B^T, both bf16 k-major, K mult of 32,
// K/32 >= 4. 512 thr = 8 waves (2m x 4n); per-wave 128x64 -> acc[8][4].
//
// LDS: 4-deep ring of 32KB K-tiles (A 16KB + B 16KB), fragment-identity
// chunks: chunk q holds, at lane offset L*16B, A[m0+q*16+(L&15)][(L>>4)*8..+8]
// so ds_read_b128 is linear & conflict-free and matches global_load_lds's
// linear dest (per-lane pre-swizzled global source).
//
// Schedule (T3+T4+T5, m201 template): 2 phases per K-tile, each phase =
//   { ds_read fragment subset ; stage ONE operand of tile t+3 (2 gl16) ;
//     s_barrier ; lgkmcnt(0) ; setprio(1) ; 16 MFMA ; setprio(0) ; s_barrier }
// Counted vmcnt(8) once per tile (before the publishing barrier of ph1):
// leaves stages of tiles t+2,t+3 (8 loads) in flight, guarantees tile t+1
// resident behind the barrier. Never drains to 0 in the main loop; epilogue
// drains 8 -> 4 -> 0.
//
// Overwrite hazard: stage of tile t+3 lands in slot (t-1)&3; every wave's
// reads of tile t-1 completed (per-phase lgkmcnt(0) before MFMA) before the
// barrier ending tile t-1, and the stage is issued after that barrier.
// ---------------------------------------------------------------------------
__device__ __forceinline__ void gemm256(
    const u16* __restrict__ A, int sA,
    const u16* __restrict__ B, int sB,
    int K, int m0, int n0,
    u16* lds, f32x4 acc[8][4])
{
    const int t   = threadIdx.x;
    const int w   = t >> 6, L = t & 63;
    const int rL  = L & 15, kq = L >> 4;
    const int qa  = 2*w;          // this wave's stage chunk pair
    const int ia0 = 8*(w>>2);     // A-frag tile base (m)
    const int jb0 = 4*(w&3);      // B-frag tile base (n)

    const size_t ga0 = (size_t)(m0 + qa*16 + rL)*sA + kq*8;
    const size_t ga1 = ga0 + (size_t)16*sA;
    const size_t gb0 = (size_t)(n0 + qa*16 + rL)*sB + kq*8;
    const size_t gb1 = gb0 + (size_t)16*sB;

    const int NT = K >> 5;
    bf16x8 av[8], bv[4];

#define STAGE_A(tile) { const size_t k0=(size_t)(tile)*32; \
    u16* sb = lds + ((tile)&3)*16384; \
    gl16(A + ga0 + k0, sb + qa*512); \
    gl16(A + ga1 + k0, sb + qa*512 + 512); }
#define STAGE_B(tile) { const size_t k0=(size_t)(tile)*32; \
    u16* sb = lds + ((tile)&3)*16384; \
    gl16(B + gb0 + k0, sb + 8192 + qa*512); \
    gl16(B + gb1 + k0, sb + 8192 + qa*512 + 512); }

#define MEMB  asm volatile("" ::: "memory")
#define BAR   __builtin_amdgcn_s_barrier()
#define LGKM0 asm volatile("s_waitcnt lgkmcnt(0)" ::: "memory")
#define VM(n) asm volatile("s_waitcnt vmcnt(" #n ")" ::: "memory")

#define PH0(tile, DOSTAGE) { \
    const u16* sb = lds + ((tile)&3)*16384; \
    _Pragma("unroll") \
    for (int i = 0; i < 4; ++i) av[i] = *(const bf16x8*)&sb[(ia0+i)*512 + L*8]; \
    _Pragma("unroll") \
    for (int j = 0; j < 4; ++j) bv[j] = *(const bf16x8*)&sb[8192 + (jb0+j)*512 + L*8]; \
    if (DOSTAGE) STAGE_A((tile)+3); \
    MEMB; BAR; LGKM0; \
    __builtin_amdgcn_s_setprio(1); \
    _Pragma("unroll") \
    for (int i = 0; i < 4; ++i) \
        _Pragma("unroll") \
        for (int j = 0; j < 4; ++j) \
            acc[i][j] = __builtin_amdgcn_mfma_f32_16x16x32_bf16(av[i], bv[j], acc[i][j], 0,0,0); \
    __builtin_amdgcn_s_setprio(0); \
    MEMB; BAR; }

#define PH1(tile, DOSTAGE, WAIT) { \
    const u16* sb = lds + ((tile)&3)*16384; \
    _Pragma("unroll") \
    for (int i = 0; i < 4; ++i) av[4+i] = *(const bf16x8*)&sb[(ia0+4+i)*512 + L*8]; \
    if (DOSTAGE) STAGE_B((tile)+3); \
    MEMB; BAR; LGKM0; \
    __builtin_amdgcn_s_setprio(1); \
    _Pragma("unroll") \
    for (int i = 0; i < 4; ++i) \
        _Pragma("unroll") \
        for (int j = 0; j < 4; ++j) \
            acc[4+i][j] = __builtin_amdgcn_mfma_f32_16x16x32_bf16(av[4+i], bv[j], acc[4+i][j], 0,0,0); \
    __builtin_amdgcn_s_setprio(0); \
    WAIT; MEMB; BAR; }

    // prologue: stage tiles 0,1,2 (12 loads); vmcnt(8) completes tile 0
    STAGE_A(0); STAGE_B(0);
    STAGE_A(1); STAGE_B(1);
    STAGE_A(2); STAGE_B(2);
    VM(8); BAR;

    for (int tt = 0; tt < NT-3; ++tt) {
        PH0(tt, 1);
        PH1(tt, 1, VM(8));
    }
    PH0(NT-3, 0); PH1(NT-3, 0, VM(4));
    PH0(NT-2, 0); PH1(NT-2, 0, VM(0));
    PH0(NT-1, 0); PH1(NT-1, 0, (void)0);

#undef STAGE_A
#undef STAGE_B
#undef PH0
#undef PH1
#undef MEMB
#undef BAR
#undef LGKM0
#undef VM
}

// ---------------------------------------------------------------------------
// elementwise: fp32 -> bf16
// ---------------------------------------------------------------------------
__global__ __launch_bounds__(256)
void cvt_bf16(const float* __restrict__ x, u16* __restrict__ y) {
    size_t i = ((size_t)blockIdx.x*256 + threadIdx.x)*4;
    float4 v = *(const float4*)&x[i];
    ushort4 h;
    h.x = f2bf(v.x); h.y = f2bf(v.y); h.z = f2bf(v.z); h.w = f2bf(v.w);
    *(ushort4*)&y[i] = h;
}

// ---------------------------------------------------------------------------
// QKV GEMM: A = Xbf, B = Wbf. Epilogue:
//   Q region: pre-scaled by 1/32, bf16, row-major  (pair-packed u32 stores)
//   K region: bf16, row-major                      (pair-packed u32 stores)
//   V region: bf16, transposed [b][d][s]           (ushort4 stores)
// ---------------------------------------------------------------------------
__global__ __launch_bounds__(512,2)
void gemm_qkv(const u16* __restrict__ Xbf, const u16* __restrict__ Wbf,
              const float* __restrict__ bias,
              u16* __restrict__ Qh, u16* __restrict__ Kh,
              u16* __restrict__ Vth)
{
    __shared__ __align__(16) u16 lds[65536];   // 128 KB ring
    f32x4 acc[8][4];
    #pragma unroll
    for (int i=0;i<8;++i)
        #pragma unroll
        for (int j=0;j<4;++j) acc[i][j] = (f32x4){0.f,0.f,0.f,0.f};

    const int m0 = blockIdx.y*256, n0 = blockIdx.x*256;
    gemm256(Xbf, DIM, Wbf, DIM, DIM, m0, n0, lds, acc);

    const int t = threadIdx.x, w = t>>6, L = t&63;
    const int wm = 128*(w>>2), wn = 64*(w&3);
    const int cl = L&15, rq = (L>>4)*4;
    const int region = n0 >> 10;           // whole 256-block in one region
    const float qscale = 0.03125f;

    if (region < 2) {
        u16* Dst = region ? Kh : Qh;
        const float fs = region ? 1.0f : qscale;
        #pragma unroll
        for (int j = 0; j < 4; ++j) {
            float bc = bias[n0 + wn + j*16 + cl];
            #pragma unroll
            for (int i = 0; i < 8; ++i)
                #pragma unroll
                for (int r = 0; r < 4; ++r)
                    acc[i][j][r] = (acc[i][j][r] + bc)*fs;
        }
        const int d0 = (n0 & 1023) + wn;
        #pragma unroll
        for (int p = 0; p < 2; ++p) {
            const int nt0 = 2*p, nt1 = 2*p+1;
            #pragma unroll
            for (int i = 0; i < 8; ++i) {
                int row0 = m0 + wm + i*16 + rq;
                int bi = row0 >> 12, s0 = row0 & (SEQ-1);
                #pragma unroll
                for (int r = 0; r < 4; ++r) {
                    float v0 = acc[i][nt0][r], v1 = acc[i][nt1][r];
                    float x0 = __shfl_xor(v0, 1, 64);
                    float x1 = __shfl_xor(v1, 1, 64);
                    unsigned wv; int colb;
                    if ((cl & 1) == 0) {
                        wv   = (unsigned)f2bf(v0) | ((unsigned)f2bf(x0) << 16);
                        colb = nt0*16 + cl;
                    } else {
                        wv   = (unsigned)f2bf(x1) | ((unsigned)f2bf(v1) << 16);
                        colb = nt1*16 + (cl-1);
                    }
                    size_t idx = ((size_t)bi*SEQ + s0 + r)*DIM + d0 + colb;
                    *(unsigned*)&Dst[idx] = wv;
                }
            }
        }
    } else {
        #pragma unroll
        for (int j = 0; j < 4; ++j) {
            int col = n0 + wn + j*16 + cl;
            float bc = bias[col];
            int d = col & (DIM-1);
            #pragma unroll
            for (int i = 0; i < 8; ++i) {
                int row0 = m0 + wm + i*16 + rq;
                int bi = row0 >> 12, s0 = row0 & (SEQ-1);
                ushort4 hv;
                hv.x = f2bf(acc[i][j][0] + bc);
                hv.y = f2bf(acc[i][j][1] + bc);
                hv.z = f2bf(acc[i][j][2] + bc);
                hv.w = f2bf(acc[i][j][3] + bc);
                size_t base = ((size_t)bi*DIM + d)*SEQ + s0;
                *(ushort4*)&Vth[base] = hv;
            }
        }
    }
}

// ---------------------------------------------------------------------------
// Scores, all batches: S_b = Qscaled_b @ K_b^T -> bf16, pair-packed stores.
// ---------------------------------------------------------------------------
__global__ __launch_bounds__(512,2)
void gemm_scores(const u16* __restrict__ Qh, const u16* __restrict__ Kh,
                 u16* __restrict__ S0, u16* __restrict__ S1,
                 u16* __restrict__ S2, u16* __restrict__ S3)
{
    __shared__ __align__(16) u16 lds[65536];
    f32x4 acc[8][4];
    #pragma unroll
    for (int i=0;i<8;++i)
        #pragma unroll
        for (int j=0;j<4;++j) acc[i][j] = (f32x4){0.f,0.f,0.f,0.f};

    const int bz = blockIdx.z;
    const size_t qo = (size_t)bz*SEQ*DIM;
    const int m0 = blockIdx.y*256, n0 = blockIdx.x*256;
    gemm256(Qh + qo, DIM, Kh + qo, DIM, DIM, m0, n0, lds, acc);

    u16* Sb = (bz == 0) ? S0 : (bz == 1) ? S1 : (bz == 2) ? S2 : S3;
    const int t = threadIdx.x, w = t>>6, L = t&63;
    const int wm = 128*(w>>2), wn = 64*(w&3);
    const int cl = L&15, rq = (L>>4)*4;
    #pragma unroll
    for (int p = 0; p < 2; ++p) {
        const int nt0 = 2*p, nt1 = 2*p+1;
        #pragma unroll
        for (int i = 0; i < 8; ++i) {
            int row0 = m0 + wm + i*16 + rq;
            #pragma unroll
            for (int r = 0; r < 4; ++r) {
                float v0 = acc[i][nt0][r], v1 = acc[i][nt1][r];
                float x0 = __shfl_xor(v0, 1, 64);
                float x1 = __shfl_xor(v1, 1, 64);
                unsigned wv; int colb;
                if ((cl & 1) == 0) {
                    wv   = (unsigned)f2bf(v0) | ((unsigned)f2bf(x0) << 16);
                    colb = nt0*16 + cl;
                } else {
                    wv   = (unsigned)f2bf(x1) | ((unsigned)f2bf(v1) << 16);
                    colb = nt1*16 + (cl-1);
                }
                *(unsigned*)&Sb[(size_t)(row0 + r)*SEQ + n0 + wn + colb] = wv;
            }
        }
    }
}

// ---------------------------------------------------------------------------
// Row softmax over bf16 S (pre-scaled scores), P bf16 in place. 16384 rows.
// ---------------------------------------------------------------------------
__global__ __launch_bounds__(256)
void softmax_pack(u16* __restrict__ S0, u16* __restrict__ S1,
                  u16* __restrict__ S2, u16* __restrict__ S3)
{
    __shared__ float red[4];
    const int t = threadIdx.x, L = t & 63, w = t >> 6;
    const int gr = blockIdx.x, bz = gr >> 12, rr = gr & (SEQ-1);
    u16* Sb = (bz == 0) ? S0 : (bz == 1) ? S1 : (bz == 2) ? S2 : S3;
    u16* row = Sb + (size_t)rr*SEQ;

    float v[16];
    float m = -1e30f;
    #pragma unroll
    for (int j = 0; j < 2; ++j) {
        ushort4 x0 = *(const ushort4*)&row[t*8 + j*2048];
        ushort4 x1 = *(const ushort4*)&row[t*8 + j*2048 + 4];
        union { unsigned u; float f; } c;
        c.u = (unsigned)x0.x << 16; v[8*j+0] = c.f;
        c.u = (unsigned)x0.y << 16; v[8*j+1] = c.f;
        c.u = (unsigned)x0.z << 16; v[8*j+2] = c.f;
        c.u = (unsigned)x0.w << 16; v[8*j+3] = c.f;
        c.u = (unsigned)x1.x << 16; v[8*j+4] = c.f;
        c.u = (unsigned)x1.y << 16; v[8*j+5] = c.f;
        c.u = (unsigned)x1.z << 16; v[8*j+6] = c.f;
        c.u = (unsigned)x1.w << 16; v[8*j+7] = c.f;
    }
    #pragma unroll
    for (int i = 0; i < 16; ++i) m = fmaxf(m, v[i]);
    #pragma unroll
    for (int off = 32; off; off >>= 1) m = fmaxf(m, __shfl_xor(m, off, 64));
    if (L == 0) red[w] = m;
    __syncthreads();
    m = fmaxf(fmaxf(red[0],red[1]), fmaxf(red[2],red[3]));

    float s = 0.f;
    #pragma unroll
    for (int i = 0; i < 16; ++i) { v[i] = __expf(v[i] - m); s += v[i]; }
    #pragma unroll
    for (int off = 32; off; off >>= 1) s += __shfl_xor(s, off, 64);
    __syncthreads();
    if (L == 0) red[w] = s;
    __syncthreads();
    s = red[0]+red[1]+red[2]+red[3];
    const float inv = 1.0f / s;

    #pragma unroll
    for (int j = 0; j < 2; ++j) {
        ushort4 h0, h1;
        h0.x = f2bf(v[8*j+0]*inv); h0.y = f2bf(v[8*j+1]*inv);
        h0.z = f2bf(v[8*j+2]*inv); h0.w = f2bf(v[8*j+3]*inv);
        h1.x = f2bf(v[8*j+4]*inv); h1.y = f2bf(v[8*j+5]*inv);
        h1.z = f2bf(v[8*j+6]*inv); h1.w = f2bf(v[8*j+7]*inv);
        *(ushort4*)&row[t*8 + j*2048]     = h0;
        *(ushort4*)&row[t*8 + j*2048 + 4] = h1;
    }
}

// ---------------------------------------------------------------------------
// PV, all batches: O_b = P_b @ Vt_b^T -> fp32 (scalar stores = full lines)
// ---------------------------------------------------------------------------
__global__ __launch_bounds__(512,2)
void gemm_pv(const u16* __restrict__ P0, const u16* __restrict__ P1,
             const u16* __restrict__ P2, const u16* __restrict__ P3,
             const u16* __restrict__ Vth,
             float* __restrict__ O0, float* __restrict__ O1,
             float* __restrict__ O2, float* __restrict__ O3)
{
    __shared__ __align__(16) u16 lds[65536];
    f32x4 acc[8][4];
    #pragma unroll
    for (int i=0;i<8;++i)
        #pragma unroll
        for (int j=0;j<4;++j) acc[i][j] = (f32x4){0.f,0.f,0.f,0.f};

    const int bz = blockIdx.z;
    const u16* Pb = (bz == 0) ? P0 : (bz == 1) ? P1 : (bz == 2) ? P2 : P3;
    float*     Ob = (bz == 0) ? O0 : (bz == 1) ? O1 : (bz == 2) ? O2 : O3;
    const int m0 = blockIdx.y*256, n0 = blockIdx.x*256;
    gemm256(Pb, SEQ, Vth + (size_t)bz*DIM*SEQ, SEQ, SEQ, m0, n0, lds, acc);

    const int t = threadIdx.x, w = t>>6, L = t&63;
    const int wm = 128*(w>>2), wn = 64*(w&3);
    const int cl = L&15, rq = (L>>4)*4;
    #pragma unroll
    for (int j = 0; j < 4; ++j) {
        int col = n0 + wn + j*16 + cl;
        #pragma unroll
        for (int i = 0; i < 8; ++i) {
            int row0 = m0 + wm + i*16 + rq;
            #pragma unroll
            for (int r = 0; r < 4; ++r)
                Ob[(size_t)(row0 + r)*DIM + col] = acc[i][j][r];
        }
    }
}

// ---------------------------------------------------------------------------
// linear copy (float4), for O2/O3 parked in ws -> d_out second half
// ---------------------------------------------------------------------------
__global__ __launch_bounds__(256)
void copy_out(const float* __restrict__ src, float* __restrict__ dst)
{
    size_t i = ((size_t)blockIdx.x*256 + threadIdx.x)*4;
    *(float4*)&dst[i] = *(const float4*)&src[i];
}

// ---------------------------------------------------------------------------
extern "C" void kernel_launch(void* const* d_in, const int* in_sizes, int n_in,
                              void* d_out, int out_size, void* d_ws, size_t ws_size,
                              hipStream_t stream) {
    const float* X    = (const float*)d_in[0];
    const float* W    = (const float*)d_in[1];
    const float* bias = (const float*)d_in[2];
    float* out = (float*)d_out;

    const size_t MB = (size_t)1 << 20;
    if (ws_size < 192*MB) return;
    char* ws = (char*)d_ws;
    char* wo = (char*)d_out;
    // ws: Qh[0,32) Kh[32,64) Vth[64,96) S0[96,128) S1[128,160) S2[160,192)
    u16* Qh  = (u16*)ws;
    u16* Kh  = (u16*)(ws + 32*MB);
    u16* Vth = (u16*)(ws + 64*MB);
    u16* S0  = (u16*)(ws + 96*MB);
    u16* S1  = (u16*)(ws + 128*MB);
    u16* S2  = (u16*)(ws + 160*MB);
    // d_out during prologue: Xbf[0,32) Wbf[32,38); during attention: S3[32,64)
    u16* Xbf = (u16*)wo;
    u16* Wbf = (u16*)(wo + 32*MB);
    u16* S3  = (u16*)(wo + 32*MB);
    // pv outputs: O0,O1 -> d_out[0,32); O2,O3 -> dead Qh/Kh-front ws[0,32)
    float* O0 = (float*)wo;
    float* O1 = (float*)(wo + 16*MB);
    float* O2 = (float*)ws;
    float* O3 = (float*)(ws + 16*MB);

    cvt_bf16<<<MTOT*DIM/1024, 256, 0, stream>>>(X, Xbf);
    cvt_bf16<<<E3*DIM/1024,   256, 0, stream>>>(W, Wbf);

    gemm_qkv<<<dim3(E3/256, MTOT/256), 512, 0, stream>>>(
        Xbf, Wbf, bias, Qh, Kh, Vth);

    gemm_scores<<<dim3(SEQ/256, SEQ/256, BATCH), 512, 0, stream>>>(
        Qh, Kh, S0, S1, S2, S3);

    softmax_pack<<<MTOT, 256, 0, stream>>>(S0, S1, S2, S3);

    gemm_pv<<<dim3(DIM/256, SEQ/256, BATCH), 512, 0, stream>>>(
        S0, S1, S2, S3, Vth, O0, O1, O2, O3);

    // O2,O3 (32 MB in ws) -> d_out[32,64)
    copy_out<<<(32*MB/sizeof(float))/1024, 256, 0, stream>>>(
        (const float*)ws, out + 8*MB);   // 8M floats = 32 MB offset
}

// Round 3
// 612.912 us; speedup vs baseline: 1.0041x; 1.0041x over previous
//
#include <hip/hip_runtime.h>
#include <cstdint>

typedef unsigned short u16;
typedef __attribute__((ext_vector_type(8))) short bf16x8;
typedef __attribute__((ext_vector_type(4))) float f32x4;

#define DIM   1024
#define BATCH 4
#define SEQ   4096
#define E3    3072
#define MTOT  (BATCH*SEQ)   // 16384

// ---------- bf16 helpers (RNE) ----------
__device__ __forceinline__ u16 f2bf(float x) {
    union { float f; unsigned u; } v; v.f = x;
    unsigned r = v.u + 0x7FFFu + ((v.u >> 16) & 1u);
    return (u16)(r >> 16);
}

// ---------- async global->LDS 16B ----------
__device__ __forceinline__ void gl16(const void* g, void* l) {
    __builtin_amdgcn_global_load_lds(
        (const __attribute__((address_space(1))) void*)g,
        (__attribute__((address_space(3))) void*)l, 16, 0, 0);
}

// ---------------------------------------------------------------------------
// GEMM mainloop: C[256x256] += A * B^T, both bf16 k-major, K mult of 32,
// K/32 >= 8 and (K/32) % 4 == 0. 512 thr = 8 waves (2m x 4n); per-wave
// 128x64 -> acc[8][4].
//
// LDS: 4-deep ring of 32KB K-tiles, fragment-identity chunks (linear
// ds_read_b128, 0 bank conflicts, matches global_load_lds linear dest).
//
// R/M overlap (the round-2 lesson: phases that read-then-MFMA the SAME
// frags serialize LDS (1155cy) with MFMA (1240cy) per tile):
// register-pipeline one phase ahead --
//   phA(t): ds_read av1(t)          ; stage A(t+3); MFMA av0 x bv  (acc 0..3)
//           vmcnt(6) -> publish t+1 ; barrier
//   phB(t): ds_read av0(t+1), bv(t+1); stage B(t+3); MFMA av1 x bv (acc 4..7)
//           barrier
// Every ds_read issues under the previous MFMA cluster; compiler inserts
// counted lgkmcnt (prefetch reads are strictly newer in the DS queue).
// Register lifetimes: av0 dead after phA, av1 dead after phB -> single
// buffers; only bv needs ping-pong (bvE/bvO) -> 2-tile unrolled loop.
//
// vmcnt(6) at phA(t): outstanding after issuing A(t+3) is
// {A(t+2),B(t+2),A(t+3)} + {A(t+1),B(t+1)} -> waiting to 6 completes B(t+1)
// = tile t+1 staged; barrier publishes cross-wave. Never drains to 0 in the
// main loop; epilogue 6 -> 4 -> 0.
//
// Overwrite hazard: stage of t+3 lands in slot (t-1)&3; all waves' reads of
// t-1 complete before their phB(t-1) MFMA (lgkm), which precedes the
// phB(t-1) barrier; stage is issued after that barrier.
// ---------------------------------------------------------------------------
__device__ __forceinline__ void gemm256(
    const u16* __restrict__ A, int sA,
    const u16* __restrict__ B, int sB,
    int K, int m0, int n0,
    u16* lds, f32x4 acc[8][4])
{
    const int t   = threadIdx.x;
    const int w   = t >> 6, L = t & 63;
    const int rL  = L & 15, kq = L >> 4;
    const int qa  = 2*w;          // this wave's stage chunk pair
    const int ia0 = 8*(w>>2);     // A-frag tile base (m)
    const int jb0 = 4*(w&3);      // B-frag tile base (n)

    const size_t ga0 = (size_t)(m0 + qa*16 + rL)*sA + kq*8;
    const size_t ga1 = ga0 + (size_t)16*sA;
    const size_t gb0 = (size_t)(n0 + qa*16 + rL)*sB + kq*8;
    const size_t gb1 = gb0 + (size_t)16*sB;

    const int NT = K >> 5;
    bf16x8 av0[4], av1[4], bvE[4], bvO[4];

#define STAGE_A(tile) { const size_t k0=(size_t)(tile)*32; \
    u16* sb = lds + ((tile)&3)*16384; \
    gl16(A + ga0 + k0, sb + qa*512); \
    gl16(A + ga1 + k0, sb + qa*512 + 512); }
#define STAGE_B(tile) { const size_t k0=(size_t)(tile)*32; \
    u16* sb = lds + ((tile)&3)*16384; \
    gl16(B + gb0 + k0, sb + 8192 + qa*512); \
    gl16(B + gb1 + k0, sb + 8192 + qa*512 + 512); }

#define MEMB  asm volatile("" ::: "memory")
#define BAR   __builtin_amdgcn_s_barrier()
#define VM(n) asm volatile("s_waitcnt vmcnt(" #n ")" ::: "memory")
#define NOP   ((void)0)

// phA(t): prefetch av1(t) under MFMA(av0 x BV); publish t+1 at end.
#define PHA(tile, BV, DOSTAGE, PUBWAIT) { \
    const u16* sb = lds + ((tile)&3)*16384; \
    _Pragma("unroll") \
    for (int i = 0; i < 4; ++i) av1[i] = *(const bf16x8*)&sb[(ia0+4+i)*512 + L*8]; \
    if (DOSTAGE) STAGE_A((tile)+3); \
    MEMB; \
    __builtin_amdgcn_s_setprio(1); \
    _Pragma("unroll") \
    for (int i = 0; i < 4; ++i) \
        _Pragma("unroll") \
        for (int j = 0; j < 4; ++j) \
            acc[i][j] = __builtin_amdgcn_mfma_f32_16x16x32_bf16(av0[i], BV[j], acc[i][j], 0,0,0); \
    __builtin_amdgcn_s_setprio(0); \
    PUBWAIT; MEMB; BAR; }

// phB(t): prefetch av0(t+1), BV_NXT(t+1) under MFMA(av1 x BV_CUR).
#define PHB(tile, BV_CUR, BV_NXT, DOSTAGE, DOREAD) { \
    const u16* sbn = lds + (((tile)+1)&3)*16384; \
    if (DOREAD) { \
        _Pragma("unroll") \
        for (int i = 0; i < 4; ++i) av0[i] = *(const bf16x8*)&sbn[(ia0+i)*512 + L*8]; \
        _Pragma("unroll") \
        for (int j = 0; j < 4; ++j) BV_NXT[j] = *(const bf16x8*)&sbn[8192 + (jb0+j)*512 + L*8]; \
    } \
    if (DOSTAGE) STAGE_B((tile)+3); \
    MEMB; \
    __builtin_amdgcn_s_setprio(1); \
    _Pragma("unroll") \
    for (int i = 0; i < 4; ++i) \
        _Pragma("unroll") \
        for (int j = 0; j < 4; ++j) \
            acc[4+i][j] = __builtin_amdgcn_mfma_f32_16x16x32_bf16(av1[i], BV_CUR[j], acc[4+i][j], 0,0,0); \
    __builtin_amdgcn_s_setprio(0); \
    MEMB; BAR; }

    // prologue: stage tiles 0,1,2; vmcnt(8) completes tile 0; read its frags
    STAGE_A(0); STAGE_B(0);
    STAGE_A(1); STAGE_B(1);
    STAGE_A(2); STAGE_B(2);
    VM(8); BAR;
    {
        const u16* sb = lds;
        #pragma unroll
        for (int i = 0; i < 4; ++i) av0[i] = *(const bf16x8*)&sb[(ia0+i)*512 + L*8];
        #pragma unroll
        for (int j = 0; j < 4; ++j) bvE[j] = *(const bf16x8*)&sb[8192 + (jb0+j)*512 + L*8];
    }

    // main loop: tiles 0 .. NT-5, 2-tile unrolled (bv ping-pong)
    for (int tt = 0; tt < NT-4; tt += 2) {
        PHA(tt,   bvE, 1, VM(6));  PHB(tt,   bvE, bvO, 1, 1);
        PHA(tt+1, bvO, 1, VM(6));  PHB(tt+1, bvO, bvE, 1, 1);
    }
    // peel: NT-4 (E, stage), NT-3 (O), NT-2 (E), NT-1 (O)
    PHA(NT-4, bvE, 1, VM(6));  PHB(NT-4, bvE, bvO, 1, 1);
    PHA(NT-3, bvO, 0, VM(4));  PHB(NT-3, bvO, bvE, 0, 1);
    PHA(NT-2, bvE, 0, VM(0));  PHB(NT-2, bvE, bvO, 0, 1);
    PHA(NT-1, bvO, 0, NOP);    PHB(NT-1, bvO, bvE, 0, 0);

#undef STAGE_A
#undef STAGE_B
#undef PHA
#undef PHB
#undef MEMB
#undef BAR
#undef VM
#undef NOP
}

// ---------------------------------------------------------------------------
// elementwise: fp32 -> bf16
// ---------------------------------------------------------------------------
__global__ __launch_bounds__(256)
void cvt_bf16(const float* __restrict__ x, u16* __restrict__ y) {
    size_t i = ((size_t)blockIdx.x*256 + threadIdx.x)*4;
    float4 v = *(const float4*)&x[i];
    ushort4 h;
    h.x = f2bf(v.x); h.y = f2bf(v.y); h.z = f2bf(v.z); h.w = f2bf(v.w);
    *(ushort4*)&y[i] = h;
}

// ---------------------------------------------------------------------------
// QKV GEMM: A = Xbf, B = Wbf. Epilogue:
//   Q region: pre-scaled by 1/32, bf16, row-major  (pair-packed u32 stores)
//   K region: bf16, row-major                      (pair-packed u32 stores)
//   V region: bf16, transposed [b][d][s]           (ushort4 stores)
// ---------------------------------------------------------------------------
__global__ __launch_bounds__(512,2)
void gemm_qkv(const u16* __restrict__ Xbf, const u16* __restrict__ Wbf,
              const float* __restrict__ bias,
              u16* __restrict__ Qh, u16* __restrict__ Kh,
              u16* __restrict__ Vth)
{
    __shared__ __align__(16) u16 lds[65536];   // 128 KB ring
    f32x4 acc[8][4];
    #pragma unroll
    for (int i=0;i<8;++i)
        #pragma unroll
        for (int j=0;j<4;++j) acc[i][j] = (f32x4){0.f,0.f,0.f,0.f};

    const int m0 = blockIdx.y*256, n0 = blockIdx.x*256;
    gemm256(Xbf, DIM, Wbf, DIM, DIM, m0, n0, lds, acc);

    const int t = threadIdx.x, w = t>>6, L = t&63;
    const int wm = 128*(w>>2), wn = 64*(w&3);
    const int cl = L&15, rq = (L>>4)*4;
    const int region = n0 >> 10;           // whole 256-block in one region
    const float qscale = 0.03125f;

    if (region < 2) {
        u16* Dst = region ? Kh : Qh;
        const float fs = region ? 1.0f : qscale;
        #pragma unroll
        for (int j = 0; j < 4; ++j) {
            float bc = bias[n0 + wn + j*16 + cl];
            #pragma unroll
            for (int i = 0; i < 8; ++i)
                #pragma unroll
                for (int r = 0; r < 4; ++r)
                    acc[i][j][r] = (acc[i][j][r] + bc)*fs;
        }
        const int d0 = (n0 & 1023) + wn;
        #pragma unroll
        for (int p = 0; p < 2; ++p) {
            const int nt0 = 2*p, nt1 = 2*p+1;
            #pragma unroll
            for (int i = 0; i < 8; ++i) {
                int row0 = m0 + wm + i*16 + rq;
                int bi = row0 >> 12, s0 = row0 & (SEQ-1);
                #pragma unroll
                for (int r = 0; r < 4; ++r) {
                    float v0 = acc[i][nt0][r], v1 = acc[i][nt1][r];
                    float x0 = __shfl_xor(v0, 1, 64);
                    float x1 = __shfl_xor(v1, 1, 64);
                    unsigned wv; int colb;
                    if ((cl & 1) == 0) {
                        wv   = (unsigned)f2bf(v0) | ((unsigned)f2bf(x0) << 16);
                        colb = nt0*16 + cl;
                    } else {
                        wv   = (unsigned)f2bf(x1) | ((unsigned)f2bf(v1) << 16);
                        colb = nt1*16 + (cl-1);
                    }
                    size_t idx = ((size_t)bi*SEQ + s0 + r)*DIM + d0 + colb;
                    *(unsigned*)&Dst[idx] = wv;
                }
            }
        }
    } else {
        #pragma unroll
        for (int j = 0; j < 4; ++j) {
            int col = n0 + wn + j*16 + cl;
            float bc = bias[col];
            int d = col & (DIM-1);
            #pragma unroll
            for (int i = 0; i < 8; ++i) {
                int row0 = m0 + wm + i*16 + rq;
                int bi = row0 >> 12, s0 = row0 & (SEQ-1);
                ushort4 hv;
                hv.x = f2bf(acc[i][j][0] + bc);
                hv.y = f2bf(acc[i][j][1] + bc);
                hv.z = f2bf(acc[i][j][2] + bc);
                hv.w = f2bf(acc[i][j][3] + bc);
                size_t base = ((size_t)bi*DIM + d)*SEQ + s0;
                *(ushort4*)&Vth[base] = hv;
            }
        }
    }
}

// ---------------------------------------------------------------------------
// Scores, all batches: S_b = Qscaled_b @ K_b^T -> bf16, pair-packed stores.
// ---------------------------------------------------------------------------
__global__ __launch_bounds__(512,2)
void gemm_scores(const u16* __restrict__ Qh, const u16* __restrict__ Kh,
                 u16* __restrict__ S0, u16* __restrict__ S1,
                 u16* __restrict__ S2, u16* __restrict__ S3)
{
    __shared__ __align__(16) u16 lds[65536];
    f32x4 acc[8][4];
    #pragma unroll
    for (int i=0;i<8;++i)
        #pragma unroll
        for (int j=0;j<4;++j) acc[i][j] = (f32x4){0.f,0.f,0.f,0.f};

    const int bz = blockIdx.z;
    const size_t qo = (size_t)bz*SEQ*DIM;
    const int m0 = blockIdx.y*256, n0 = blockIdx.x*256;
    gemm256(Qh + qo, DIM, Kh + qo, DIM, DIM, m0, n0, lds, acc);

    u16* Sb = (bz == 0) ? S0 : (bz == 1) ? S1 : (bz == 2) ? S2 : S3;
    const int t = threadIdx.x, w = t>>6, L = t&63;
    const int wm = 128*(w>>2), wn = 64*(w&3);
    const int cl = L&15, rq = (L>>4)*4;
    #pragma unroll
    for (int p = 0; p < 2; ++p) {
        const int nt0 = 2*p, nt1 = 2*p+1;
        #pragma unroll
        for (int i = 0; i < 8; ++i) {
            int row0 = m0 + wm + i*16 + rq;
            #pragma unroll
            for (int r = 0; r < 4; ++r) {
                float v0 = acc[i][nt0][r], v1 = acc[i][nt1][r];
                float x0 = __shfl_xor(v0, 1, 64);
                float x1 = __shfl_xor(v1, 1, 64);
                unsigned wv; int colb;
                if ((cl & 1) == 0) {
                    wv   = (unsigned)f2bf(v0) | ((unsigned)f2bf(x0) << 16);
                    colb = nt0*16 + cl;
                } else {
                    wv   = (unsigned)f2bf(x1) | ((unsigned)f2bf(v1) << 16);
                    colb = nt1*16 + (cl-1);
                }
                *(unsigned*)&Sb[(size_t)(row0 + r)*SEQ + n0 + wn + colb] = wv;
            }
        }
    }
}

// ---------------------------------------------------------------------------
// Row softmax over bf16 S (pre-scaled scores), P bf16 in place. 16384 rows.
// ---------------------------------------------------------------------------
__global__ __launch_bounds__(256)
void softmax_pack(u16* __restrict__ S0, u16* __restrict__ S1,
                  u16* __restrict__ S2, u16* __restrict__ S3)
{
    __shared__ float red[4];
    const int t = threadIdx.x, L = t & 63, w = t >> 6;
    const int gr = blockIdx.x, bz = gr >> 12, rr = gr & (SEQ-1);
    u16* Sb = (bz == 0) ? S0 : (bz == 1) ? S1 : (bz == 2) ? S2 : S3;
    u16* row = Sb + (size_t)rr*SEQ;

    float v[16];
    float m = -1e30f;
    #pragma unroll
    for (int j = 0; j < 2; ++j) {
        ushort4 x0 = *(const ushort4*)&row[t*8 + j*2048];
        ushort4 x1 = *(const ushort4*)&row[t*8 + j*2048 + 4];
        union { unsigned u; float f; } c;
        c.u = (unsigned)x0.x << 16; v[8*j+0] = c.f;
        c.u = (unsigned)x0.y << 16; v[8*j+1] = c.f;
        c.u = (unsigned)x0.z << 16; v[8*j+2] = c.f;
        c.u = (unsigned)x0.w << 16; v[8*j+3] = c.f;
        c.u = (unsigned)x1.x << 16; v[8*j+4] = c.f;
        c.u = (unsigned)x1.y << 16; v[8*j+5] = c.f;
        c.u = (unsigned)x1.z << 16; v[8*j+6] = c.f;
        c.u = (unsigned)x1.w << 16; v[8*j+7] = c.f;
    }
    #pragma unroll
    for (int i = 0; i < 16; ++i) m = fmaxf(m, v[i]);
    #pragma unroll
    for (int off = 32; off; off >>= 1) m = fmaxf(m, __shfl_xor(m, off, 64));
    if (L == 0) red[w] = m;
    __syncthreads();
    m = fmaxf(fmaxf(red[0],red[1]), fmaxf(red[2],red[3]));

    float s = 0.f;
    #pragma unroll
    for (int i = 0; i < 16; ++i) { v[i] = __expf(v[i] - m); s += v[i]; }
    #pragma unroll
    for (int off = 32; off; off >>= 1) s += __shfl_xor(s, off, 64);
    __syncthreads();
    if (L == 0) red[w] = s;
    __syncthreads();
    s = red[0]+red[1]+red[2]+red[3];
    const float inv = 1.0f / s;

    #pragma unroll
    for (int j = 0; j < 2; ++j) {
        ushort4 h0, h1;
        h0.x = f2bf(v[8*j+0]*inv); h0.y = f2bf(v[8*j+1]*inv);
        h0.z = f2bf(v[8*j+2]*inv); h0.w = f2bf(v[8*j+3]*inv);
        h1.x = f2bf(v[8*j+4]*inv); h1.y = f2bf(v[8*j+5]*inv);
        h1.z = f2bf(v[8*j+6]*inv); h1.w = f2bf(v[8*j+7]*inv);
        *(ushort4*)&row[t*8 + j*2048]     = h0;
        *(ushort4*)&row[t*8 + j*2048 + 4] = h1;
    }
}

// ---------------------------------------------------------------------------
// PV, all batches: O_b = P_b @ Vt_b^T -> fp32 (scalar stores = full lines)
// ---------------------------------------------------------------------------
__global__ __launch_bounds__(512,2)
void gemm_pv(const u16* __restrict__ P0, const u16* __restrict__ P1,
             const u16* __restrict__ P2, const u16* __restrict__ P3,
             const u16* __restrict__ Vth,
             float* __restrict__ O0, float* __restrict__ O1,
             float* __restrict__ O2, float* __restrict__ O3)
{
    __shared__ __align__(16) u16 lds[65536];
    f32x4 acc[8][4];
    #pragma unroll
    for (int i=0;i<8;++i)
        #pragma unroll
        for (int j=0;j<4;++j) acc[i][j] = (f32x4){0.f,0.f,0.f,0.f};

    const int bz = blockIdx.z;
    const u16* Pb = (bz == 0) ? P0 : (bz == 1) ? P1 : (bz == 2) ? P2 : P3;
    float*     Ob = (bz == 0) ? O0 : (bz == 1) ? O1 : (bz == 2) ? O2 : O3;
    const int m0 = blockIdx.y*256, n0 = blockIdx.x*256;
    gemm256(Pb, SEQ, Vth + (size_t)bz*DIM*SEQ, SEQ, SEQ, m0, n0, lds, acc);

    const int t = threadIdx.x, w = t>>6, L = t&63;
    const int wm = 128*(w>>2), wn = 64*(w&3);
    const int cl = L&15, rq = (L>>4)*4;
    #pragma unroll
    for (int j = 0; j < 4; ++j) {
        int col = n0 + wn + j*16 + cl;
        #pragma unroll
        for (int i = 0; i < 8; ++i) {
            int row0 = m0 + wm + i*16 + rq;
            #pragma unroll
            for (int r = 0; r < 4; ++r)
                Ob[(size_t)(row0 + r)*DIM + col] = acc[i][j][r];
        }
    }
}

// ---------------------------------------------------------------------------
// linear copy (float4), for O2/O3 parked in ws -> d_out second half
// ---------------------------------------------------------------------------
__global__ __launch_bounds__(256)
void copy_out(const float* __restrict__ src, float* __restrict__ dst)
{
    size_t i = ((size_t)blockIdx.x*256 + threadIdx.x)*4;
    *(float4*)&dst[i] = *(const float4*)&src[i];
}

// ---------------------------------------------------------------------------
extern "C" void kernel_launch(void* const* d_in, const int* in_sizes, int n_in,
                              void* d_out, int out_size, void* d_ws, size_t ws_size,
                              hipStream_t stream) {
    const float* X    = (const float*)d_in[0];
    const float* W    = (const float*)d_in[1];
    const float* bias = (const float*)d_in[2];
    float* out = (float*)d_out;

    const size_t MB = (size_t)1 << 20;
    if (ws_size < 192*MB) return;
    char* ws = (char*)d_ws;
    char* wo = (char*)d_out;
    // ws: Qh[0,32) Kh[32,64) Vth[64,96) S0[96,128) S1[128,160) S2[160,192)
    u16* Qh  = (u16*)ws;
    u16* Kh  = (u16*)(ws + 32*MB);
    u16* Vth = (u16*)(ws + 64*MB);
    u16* S0  = (u16*)(ws + 96*MB);
    u16* S1  = (u16*)(ws + 128*MB);
    u16* S2  = (u16*)(ws + 160*MB);
    // d_out during prologue: Xbf[0,32) Wbf[32,38); during attention: S3[32,64)
    u16* Xbf = (u16*)wo;
    u16* Wbf = (u16*)(wo + 32*MB);
    u16* S3  = (u16*)(wo + 32*MB);
    // pv outputs: O0,O1 -> d_out[0,32); O2,O3 -> dead Qh/Kh-front ws[0,32)
    float* O0 = (float*)wo;
    float* O1 = (float*)(wo + 16*MB);
    float* O2 = (float*)ws;
    float* O3 = (float*)(ws + 16*MB);

    cvt_bf16<<<MTOT*DIM/1024, 256, 0, stream>>>(X, Xbf);
    cvt_bf16<<<E3*DIM/1024,   256, 0, stream>>>(W, Wbf);

    gemm_qkv<<<dim3(E3/256, MTOT/256), 512, 0, stream>>>(
        Xbf, Wbf, bias, Qh, Kh, Vth);

    gemm_scores<<<dim3(SEQ/256, SEQ/256, BATCH), 512, 0, stream>>>(
        Qh, Kh, S0, S1, S2, S3);

    softmax_pack<<<MTOT, 256, 0, stream>>>(S0, S1, S2, S3);

    gemm_pv<<<dim3(DIM/256, SEQ/256, BATCH), 512, 0, stream>>>(
        S0, S1, S2, S3, Vth, O0, O1, O2, O3);

    // O2,O3 (32 MB in ws) -> d_out[32,64)
    copy_out<<<(32*MB/sizeof(float))/1024, 256, 0, stream>>>(
        (const float*)ws, out + 8*MB);   // 8M floats = 32 MB offset
}

// Round 4
// 604.302 us; speedup vs baseline: 1.0184x; 1.0142x over previous
//
#include <hip/hip_runtime.h>
#include <cstdint>

typedef unsigned short u16;
typedef __attribute__((ext_vector_type(8))) short bf16x8;
typedef __attribute__((ext_vector_type(4))) float f32x4;

#define DIM   1024
#define BATCH 4
#define SEQ   4096
#define E3    3072
#define MTOT  (BATCH*SEQ)   // 16384

// ---------- bf16 helpers (RNE) ----------
__device__ __forceinline__ u16 f2bf(float x) {
    union { float f; unsigned u; } v; v.f = x;
    unsigned r = v.u + 0x7FFFu + ((v.u >> 16) & 1u);
    return (u16)(r >> 16);
}

// ---------- async global->LDS 16B ----------
__device__ __forceinline__ void gl16(const void* g, void* l) {
    __builtin_amdgcn_global_load_lds(
        (const __attribute__((address_space(1))) void*)g,
        (__attribute__((address_space(3))) void*)l, 16, 0, 0);
}

// ---------------------------------------------------------------------------
// GEMM mainloop: C[256x256] += A * B^T, both bf16 k-major, K mult of 32,
// K/32 >= 4. 512 thr = 8 waves (2m x 4n); per-wave 128x64 -> acc[8][4].
//
// LDS: 4-deep ring of 32KB K-tiles, fragment-identity chunks (linear
// ds_read_b128, 0 bank conflicts, matches global_load_lds linear dest).
//
// SYNC IDIOM (round-4 fix): bare asm waitcnts with NO "memory" clobber.
// Rounds 1-3 used `asm volatile(... ::: "memory")` at every phase boundary;
// the waitcnt pass treats clobbering asm as a memory op and drains counters
// (vmcnt->0) there, turning the counted-vmcnt pipeline into drain-to-zero
// every phase (~900cy HBM-latency stall each -- measured 1700cy/phase vs
// ~900cy work). m201's verified idiom: bare `s_waitcnt vmcnt(N)` +
// raw s_barrier + sched_barrier(0) fences (rule #18). No explicit lgkmcnt:
// the ds_read->MFMA register dependence makes the compiler insert COUNTED
// lgkm waits.
//
// Per tile, 2 phases (m201 shape):
//  PH0(t): ds_read av[0..3],bv[0..3](t); stage A(t+3); [fence] BAR [fence]
//          setprio(1) 16 MFMA acc[0..3] setprio(0); [fence] BAR
//  PH1(t): ds_read av[4..7](t);          stage B(t+3); [fence] BAR [fence]
//          setprio(1) 16 MFMA acc[4..7] setprio(0);
//          [fence] vmcnt(8) [fence] BAR      <- publishes tile t+1
// vmcnt(8): queue (newest first) B(t+3),A(t+3),B(t+2),A(t+2) = 8 allowed ->
// forces B(t+1)+older complete = tile t+1 staged. Never 0 in main loop;
// peel drains 8 -> 4 -> 0.
//
// Overwrite hazard: stage of t+3 lands in slot (t-1)&3; every wave's reads
// of t-1 completed (counted lgkm before their MFMA uses) before the barrier
// ending tile t-1; the stage issues after that barrier. gl16 (side-effecting
// intrinsic) cannot reorder across s_barrier; sched_barrier(0) pins the rest.
// ---------------------------------------------------------------------------
__device__ __forceinline__ void gemm256(
    const u16* __restrict__ A, int sA,
    const u16* __restrict__ B, int sB,
    int K, int m0, int n0,
    u16* lds, f32x4 acc[8][4])
{
    const int t   = threadIdx.x;
    const int w   = t >> 6, L = t & 63;
    const int rL  = L & 15, kq = L >> 4;
    const int qa  = 2*w;          // this wave's stage chunk pair
    const int ia0 = 8*(w>>2);     // A-frag tile base (m)
    const int jb0 = 4*(w&3);      // B-frag tile base (n)

    const size_t ga0 = (size_t)(m0 + qa*16 + rL)*sA + kq*8;
    const size_t ga1 = ga0 + (size_t)16*sA;
    const size_t gb0 = (size_t)(n0 + qa*16 + rL)*sB + kq*8;
    const size_t gb1 = gb0 + (size_t)16*sB;

    const int NT = K >> 5;
    bf16x8 av[8], bv[4];

#define STAGE_A(tile) { const size_t k0=(size_t)(tile)*32; \
    u16* sb = lds + ((tile)&3)*16384; \
    gl16(A + ga0 + k0, sb + qa*512); \
    gl16(A + ga1 + k0, sb + qa*512 + 512); }
#define STAGE_B(tile) { const size_t k0=(size_t)(tile)*32; \
    u16* sb = lds + ((tile)&3)*16384; \
    gl16(B + gb0 + k0, sb + 8192 + qa*512); \
    gl16(B + gb1 + k0, sb + 8192 + qa*512 + 512); }

#define FEN   __builtin_amdgcn_sched_barrier(0)
#define BARR  __builtin_amdgcn_s_barrier()
#define VMW(n) asm volatile("s_waitcnt vmcnt(" #n ")")
#define NOWAIT ((void)0)

#define PH0(tile, DOSTAGE) { \
    const u16* sb = lds + ((tile)&3)*16384; \
    _Pragma("unroll") \
    for (int i = 0; i < 4; ++i) av[i] = *(const bf16x8*)&sb[(ia0+i)*512 + L*8]; \
    _Pragma("unroll") \
    for (int j = 0; j < 4; ++j) bv[j] = *(const bf16x8*)&sb[8192 + (jb0+j)*512 + L*8]; \
    if (DOSTAGE) STAGE_A((tile)+3); \
    FEN; BARR; FEN; \
    __builtin_amdgcn_s_setprio(1); \
    _Pragma("unroll") \
    for (int i = 0; i < 4; ++i) \
        _Pragma("unroll") \
        for (int j = 0; j < 4; ++j) \
            acc[i][j] = __builtin_amdgcn_mfma_f32_16x16x32_bf16(av[i], bv[j], acc[i][j], 0,0,0); \
    __builtin_amdgcn_s_setprio(0); \
    FEN; BARR; }

#define PH1(tile, DOSTAGE, WAIT) { \
    const u16* sb = lds + ((tile)&3)*16384; \
    _Pragma("unroll") \
    for (int i = 0; i < 4; ++i) av[4+i] = *(const bf16x8*)&sb[(ia0+4+i)*512 + L*8]; \
    if (DOSTAGE) STAGE_B((tile)+3); \
    FEN; BARR; FEN; \
    __builtin_amdgcn_s_setprio(1); \
    _Pragma("unroll") \
    for (int i = 0; i < 4; ++i) \
        _Pragma("unroll") \
        for (int j = 0; j < 4; ++j) \
            acc[4+i][j] = __builtin_amdgcn_mfma_f32_16x16x32_bf16(av[4+i], bv[j], acc[4+i][j], 0,0,0); \
    __builtin_amdgcn_s_setprio(0); \
    FEN; WAIT; FEN; BARR; }

    // prologue: stage tiles 0,1,2 (12 loads/wave); vmcnt(8) completes tile 0
    STAGE_A(0); STAGE_B(0);
    STAGE_A(1); STAGE_B(1);
    STAGE_A(2); STAGE_B(2);
    FEN; VMW(8); FEN; BARR;

    for (int tt = 0; tt < NT-3; ++tt) {
        PH0(tt, 1);
        PH1(tt, 1, VMW(8));
    }
    PH0(NT-3, 0); PH1(NT-3, 0, VMW(4));
    PH0(NT-2, 0); PH1(NT-2, 0, VMW(0));
    PH0(NT-1, 0); PH1(NT-1, 0, NOWAIT);

#undef STAGE_A
#undef STAGE_B
#undef PH0
#undef PH1
#undef FEN
#undef BARR
#undef VMW
#undef NOWAIT
}

// ---------------------------------------------------------------------------
// elementwise: fp32 -> bf16
// ---------------------------------------------------------------------------
__global__ __launch_bounds__(256)
void cvt_bf16(const float* __restrict__ x, u16* __restrict__ y) {
    size_t i = ((size_t)blockIdx.x*256 + threadIdx.x)*4;
    float4 v = *(const float4*)&x[i];
    ushort4 h;
    h.x = f2bf(v.x); h.y = f2bf(v.y); h.z = f2bf(v.z); h.w = f2bf(v.w);
    *(ushort4*)&y[i] = h;
}

// ---------------------------------------------------------------------------
// QKV GEMM: A = Xbf, B = Wbf. Epilogue:
//   Q region: pre-scaled by 1/32, bf16, row-major  (pair-packed u32 stores)
//   K region: bf16, row-major                      (pair-packed u32 stores)
//   V region: bf16, transposed [b][d][s]           (ushort4 stores)
// ---------------------------------------------------------------------------
__global__ __launch_bounds__(512,2)
void gemm_qkv(const u16* __restrict__ Xbf, const u16* __restrict__ Wbf,
              const float* __restrict__ bias,
              u16* __restrict__ Qh, u16* __restrict__ Kh,
              u16* __restrict__ Vth)
{
    __shared__ __align__(16) u16 lds[65536];   // 128 KB ring
    f32x4 acc[8][4];
    #pragma unroll
    for (int i=0;i<8;++i)
        #pragma unroll
        for (int j=0;j<4;++j) acc[i][j] = (f32x4){0.f,0.f,0.f,0.f};

    const int m0 = blockIdx.y*256, n0 = blockIdx.x*256;
    gemm256(Xbf, DIM, Wbf, DIM, DIM, m0, n0, lds, acc);

    const int t = threadIdx.x, w = t>>6, L = t&63;
    const int wm = 128*(w>>2), wn = 64*(w&3);
    const int cl = L&15, rq = (L>>4)*4;
    const int region = n0 >> 10;           // whole 256-block in one region
    const float qscale = 0.03125f;

    if (region < 2) {
        u16* Dst = region ? Kh : Qh;
        const float fs = region ? 1.0f : qscale;
        #pragma unroll
        for (int j = 0; j < 4; ++j) {
            float bc = bias[n0 + wn + j*16 + cl];
            #pragma unroll
            for (int i = 0; i < 8; ++i)
                #pragma unroll
                for (int r = 0; r < 4; ++r)
                    acc[i][j][r] = (acc[i][j][r] + bc)*fs;
        }
        const int d0 = (n0 & 1023) + wn;
        #pragma unroll
        for (int p = 0; p < 2; ++p) {
            const int nt0 = 2*p, nt1 = 2*p+1;
            #pragma unroll
            for (int i = 0; i < 8; ++i) {
                int row0 = m0 + wm + i*16 + rq;
                int bi = row0 >> 12, s0 = row0 & (SEQ-1);
                #pragma unroll
                for (int r = 0; r < 4; ++r) {
                    float v0 = acc[i][nt0][r], v1 = acc[i][nt1][r];
                    float x0 = __shfl_xor(v0, 1, 64);
                    float x1 = __shfl_xor(v1, 1, 64);
                    unsigned wv; int colb;
                    if ((cl & 1) == 0) {
                        wv   = (unsigned)f2bf(v0) | ((unsigned)f2bf(x0) << 16);
                        colb = nt0*16 + cl;
                    } else {
                        wv   = (unsigned)f2bf(x1) | ((unsigned)f2bf(v1) << 16);
                        colb = nt1*16 + (cl-1);
                    }
                    size_t idx = ((size_t)bi*SEQ + s0 + r)*DIM + d0 + colb;
                    *(unsigned*)&Dst[idx] = wv;
                }
            }
        }
    } else {
        #pragma unroll
        for (int j = 0; j < 4; ++j) {
            int col = n0 + wn + j*16 + cl;
            float bc = bias[col];
            int d = col & (DIM-1);
            #pragma unroll
            for (int i = 0; i < 8; ++i) {
                int row0 = m0 + wm + i*16 + rq;
                int bi = row0 >> 12, s0 = row0 & (SEQ-1);
                ushort4 hv;
                hv.x = f2bf(acc[i][j][0] + bc);
                hv.y = f2bf(acc[i][j][1] + bc);
                hv.z = f2bf(acc[i][j][2] + bc);
                hv.w = f2bf(acc[i][j][3] + bc);
                size_t base = ((size_t)bi*DIM + d)*SEQ + s0;
                *(ushort4*)&Vth[base] = hv;
            }
        }
    }
}

// ---------------------------------------------------------------------------
// Scores, all batches: S_b = Qscaled_b @ K_b^T -> bf16, pair-packed stores.
// ---------------------------------------------------------------------------
__global__ __launch_bounds__(512,2)
void gemm_scores(const u16* __restrict__ Qh, const u16* __restrict__ Kh,
                 u16* __restrict__ S0, u16* __restrict__ S1,
                 u16* __restrict__ S2, u16* __restrict__ S3)
{
    __shared__ __align__(16) u16 lds[65536];
    f32x4 acc[8][4];
    #pragma unroll
    for (int i=0;i<8;++i)
        #pragma unroll
        for (int j=0;j<4;++j) acc[i][j] = (f32x4){0.f,0.f,0.f,0.f};

    const int bz = blockIdx.z;
    const size_t qo = (size_t)bz*SEQ*DIM;
    const int m0 = blockIdx.y*256, n0 = blockIdx.x*256;
    gemm256(Qh + qo, DIM, Kh + qo, DIM, DIM, m0, n0, lds, acc);

    u16* Sb = (bz == 0) ? S0 : (bz == 1) ? S1 : (bz == 2) ? S2 : S3;
    const int t = threadIdx.x, w = t>>6, L = t&63;
    const int wm = 128*(w>>2), wn = 64*(w&3);
    const int cl = L&15, rq = (L>>4)*4;
    #pragma unroll
    for (int p = 0; p < 2; ++p) {
        const int nt0 = 2*p, nt1 = 2*p+1;
        #pragma unroll
        for (int i = 0; i < 8; ++i) {
            int row0 = m0 + wm + i*16 + rq;
            #pragma unroll
            for (int r = 0; r < 4; ++r) {
                float v0 = acc[i][nt0][r], v1 = acc[i][nt1][r];
                float x0 = __shfl_xor(v0, 1, 64);
                float x1 = __shfl_xor(v1, 1, 64);
                unsigned wv; int colb;
                if ((cl & 1) == 0) {
                    wv   = (unsigned)f2bf(v0) | ((unsigned)f2bf(x0) << 16);
                    colb = nt0*16 + cl;
                } else {
                    wv   = (unsigned)f2bf(x1) | ((unsigned)f2bf(v1) << 16);
                    colb = nt1*16 + (cl-1);
                }
                *(unsigned*)&Sb[(size_t)(row0 + r)*SEQ + n0 + wn + colb] = wv;
            }
        }
    }
}

// ---------------------------------------------------------------------------
// Row softmax over bf16 S (pre-scaled scores), P bf16 in place. 16384 rows.
// ---------------------------------------------------------------------------
__global__ __launch_bounds__(256)
void softmax_pack(u16* __restrict__ S0, u16* __restrict__ S1,
                  u16* __restrict__ S2, u16* __restrict__ S3)
{
    __shared__ float red[4];
    const int t = threadIdx.x, L = t & 63, w = t >> 6;
    const int gr = blockIdx.x, bz = gr >> 12, rr = gr & (SEQ-1);
    u16* Sb = (bz == 0) ? S0 : (bz == 1) ? S1 : (bz == 2) ? S2 : S3;
    u16* row = Sb + (size_t)rr*SEQ;

    float v[16];
    float m = -1e30f;
    #pragma unroll
    for (int j = 0; j < 2; ++j) {
        ushort4 x0 = *(const ushort4*)&row[t*8 + j*2048];
        ushort4 x1 = *(const ushort4*)&row[t*8 + j*2048 + 4];
        union { unsigned u; float f; } c;
        c.u = (unsigned)x0.x << 16; v[8*j+0] = c.f;
        c.u = (unsigned)x0.y << 16; v[8*j+1] = c.f;
        c.u = (unsigned)x0.z << 16; v[8*j+2] = c.f;
        c.u = (unsigned)x0.w << 16; v[8*j+3] = c.f;
        c.u = (unsigned)x1.x << 16; v[8*j+4] = c.f;
        c.u = (unsigned)x1.y << 16; v[8*j+5] = c.f;
        c.u = (unsigned)x1.z << 16; v[8*j+6] = c.f;
        c.u = (unsigned)x1.w << 16; v[8*j+7] = c.f;
    }
    #pragma unroll
    for (int i = 0; i < 16; ++i) m = fmaxf(m, v[i]);
    #pragma unroll
    for (int off = 32; off; off >>= 1) m = fmaxf(m, __shfl_xor(m, off, 64));
    if (L == 0) red[w] = m;
    __syncthreads();
    m = fmaxf(fmaxf(red[0],red[1]), fmaxf(red[2],red[3]));

    float s = 0.f;
    #pragma unroll
    for (int i = 0; i < 16; ++i) { v[i] = __expf(v[i] - m); s += v[i]; }
    #pragma unroll
    for (int off = 32; off; off >>= 1) s += __shfl_xor(s, off, 64);
    __syncthreads();
    if (L == 0) red[w] = s;
    __syncthreads();
    s = red[0]+red[1]+red[2]+red[3];
    const float inv = 1.0f / s;

    #pragma unroll
    for (int j = 0; j < 2; ++j) {
        ushort4 h0, h1;
        h0.x = f2bf(v[8*j+0]*inv); h0.y = f2bf(v[8*j+1]*inv);
        h0.z = f2bf(v[8*j+2]*inv); h0.w = f2bf(v[8*j+3]*inv);
        h1.x = f2bf(v[8*j+4]*inv); h1.y = f2bf(v[8*j+5]*inv);
        h1.z = f2bf(v[8*j+6]*inv); h1.w = f2bf(v[8*j+7]*inv);
        *(ushort4*)&row[t*8 + j*2048]     = h0;
        *(ushort4*)&row[t*8 + j*2048 + 4] = h1;
    }
}

// ---------------------------------------------------------------------------
// PV, all batches: O_b = P_b @ Vt_b^T -> fp32 (scalar stores = full lines)
// ---------------------------------------------------------------------------
__global__ __launch_bounds__(512,2)
void gemm_pv(const u16* __restrict__ P0, const u16* __restrict__ P1,
             const u16* __restrict__ P2, const u16* __restrict__ P3,
             const u16* __restrict__ Vth,
             float* __restrict__ O0, float* __restrict__ O1,
             float* __restrict__ O2, float* __restrict__ O3)
{
    __shared__ __align__(16) u16 lds[65536];
    f32x4 acc[8][4];
    #pragma unroll
    for (int i=0;i<8;++i)
        #pragma unroll
        for (int j=0;j<4;++j) acc[i][j] = (f32x4){0.f,0.f,0.f,0.f};

    const int bz = blockIdx.z;
    const u16* Pb = (bz == 0) ? P0 : (bz == 1) ? P1 : (bz == 2) ? P2 : P3;
    float*     Ob = (bz == 0) ? O0 : (bz == 1) ? O1 : (bz == 2) ? O2 : O3;
    const int m0 = blockIdx.y*256, n0 = blockIdx.x*256;
    gemm256(Pb, SEQ, Vth + (size_t)bz*DIM*SEQ, SEQ, SEQ, m0, n0, lds, acc);

    const int t = threadIdx.x, w = t>>6, L = t&63;
    const int wm = 128*(w>>2), wn = 64*(w&3);
    const int cl = L&15, rq = (L>>4)*4;
    #pragma unroll
    for (int j = 0; j < 4; ++j) {
        int col = n0 + wn + j*16 + cl;
        #pragma unroll
        for (int i = 0; i < 8; ++i) {
            int row0 = m0 + wm + i*16 + rq;
            #pragma unroll
            for (int r = 0; r < 4; ++r)
                Ob[(size_t)(row0 + r)*DIM + col] = acc[i][j][r];
        }
    }
}

// ---------------------------------------------------------------------------
// linear copy (float4), for O2/O3 parked in ws -> d_out second half
// ---------------------------------------------------------------------------
__global__ __launch_bounds__(256)
void copy_out(const float* __restrict__ src, float* __restrict__ dst)
{
    size_t i = ((size_t)blockIdx.x*256 + threadIdx.x)*4;
    *(float4*)&dst[i] = *(const float4*)&src[i];
}

// ---------------------------------------------------------------------------
extern "C" void kernel_launch(void* const* d_in, const int* in_sizes, int n_in,
                              void* d_out, int out_size, void* d_ws, size_t ws_size,
                              hipStream_t stream) {
    const float* X    = (const float*)d_in[0];
    const float* W    = (const float*)d_in[1];
    const float* bias = (const float*)d_in[2];
    float* out = (float*)d_out;

    const size_t MB = (size_t)1 << 20;
    if (ws_size < 192*MB) return;
    char* ws = (char*)d_ws;
    char* wo = (char*)d_out;
    // ws: Qh[0,32) Kh[32,64) Vth[64,96) S0[96,128) S1[128,160) S2[160,192)
    u16* Qh  = (u16*)ws;
    u16* Kh  = (u16*)(ws + 32*MB);
    u16* Vth = (u16*)(ws + 64*MB);
    u16* S0  = (u16*)(ws + 96*MB);
    u16* S1  = (u16*)(ws + 128*MB);
    u16* S2  = (u16*)(ws + 160*MB);
    // d_out during prologue: Xbf[0,32) Wbf[32,38); during attention: S3[32,64)
    u16* Xbf = (u16*)wo;
    u16* Wbf = (u16*)(wo + 32*MB);
    u16* S3  = (u16*)(wo + 32*MB);
    // pv outputs: O0,O1 -> d_out[0,32); O2,O3 -> dead Qh/Kh-front ws[0,32)
    float* O0 = (float*)wo;
    float* O1 = (float*)(wo + 16*MB);
    float* O2 = (float*)ws;
    float* O3 = (float*)(ws + 16*MB);

    cvt_bf16<<<MTOT*DIM/1024, 256, 0, stream>>>(X, Xbf);
    cvt_bf16<<<E3*DIM/1024,   256, 0, stream>>>(W, Wbf);

    gemm_qkv<<<dim3(E3/256, MTOT/256), 512, 0, stream>>>(
        Xbf, Wbf, bias, Qh, Kh, Vth);

    gemm_scores<<<dim3(SEQ/256, SEQ/256, BATCH), 512, 0, stream>>>(
        Qh, Kh, S0, S1, S2, S3);

    softmax_pack<<<MTOT, 256, 0, stream>>>(S0, S1, S2, S3);

    gemm_pv<<<dim3(DIM/256, SEQ/256, BATCH), 512, 0, stream>>>(
        S0, S1, S2, S3, Vth, O0, O1, O2, O3);

    // O2,O3 (32 MB in ws) -> d_out[32,64)
    copy_out<<<(32*MB/sizeof(float))/1024, 256, 0, stream>>>(
        (const float*)ws, out + 8*MB);   // 8M floats = 32 MB offset
}

// Round 5
// 581.169 us; speedup vs baseline: 1.0590x; 1.0398x over previous
//
#include <hip/hip_runtime.h>
#include <cstdint>

typedef unsigned short u16;
typedef __attribute__((ext_vector_type(8))) short bf16x8;
typedef __attribute__((ext_vector_type(4))) float f32x4;

#define DIM   1024
#define BATCH 4
#define SEQ   4096
#define E3    3072
#define MTOT  (BATCH*SEQ)   // 16384

// ---------- bf16 helpers (RNE) ----------
__device__ __forceinline__ u16 f2bf(float x) {
    union { float f; unsigned u; } v; v.f = x;
    unsigned r = v.u + 0x7FFFu + ((v.u >> 16) & 1u);
    return (u16)(r >> 16);
}

// ---------- async global->LDS 16B ----------
__device__ __forceinline__ void gl16(const void* g, void* l) {
    __builtin_amdgcn_global_load_lds(
        (const __attribute__((address_space(1))) void*)g,
        (__attribute__((address_space(3))) void*)l, 16, 0, 0);
}

// ---------------------------------------------------------------------------
// GEMM mainloop: C[256x256] += A * B^T, both bf16 k-major, K mult of 32,
// K/32 >= 4. 512 thr = 8 waves (2m x 4n); per-wave 128x64 -> acc[8][4].
//
// ROUND-5 THEORY: rounds 1-4 (four distinct schedules) all landed at the
// SAME 3400cy/K-tile -> schedule-invariant -> FEED-bound. Staging demand at
// full MFMA rate = 32KB/tile/CU / 520ns = ~16 TB/s aggregate; without XCD
// swizzle, consecutive blocks scatter round-robin over 8 XCDs, panel reuse
// misses the private 4MB L2s, and the LLC+HBM mix feeds only ~5.7 TB/s --
// exactly the measured rate. Fix = T1 bijective XCD-chunked swizzle
// (HW: XCD = flat%8 -> c=F&7 picks the chunk, s=F>>3 walks inside it),
// giving each XCD an L2-sized contiguous block neighborhood.
// Schedule below is byte-identical to round 4 (single-lever A/B).
// ---------------------------------------------------------------------------
__device__ __forceinline__ void gemm256(
    const u16* __restrict__ A, int sA,
    const u16* __restrict__ B, int sB,
    int K, int m0, int n0,
    u16* lds, f32x4 acc[8][4])
{
    const int t   = threadIdx.x;
    const int w   = t >> 6, L = t & 63;
    const int rL  = L & 15, kq = L >> 4;
    const int qa  = 2*w;          // this wave's stage chunk pair
    const int ia0 = 8*(w>>2);     // A-frag tile base (m)
    const int jb0 = 4*(w&3);      // B-frag tile base (n)

    const size_t ga0 = (size_t)(m0 + qa*16 + rL)*sA + kq*8;
    const size_t ga1 = ga0 + (size_t)16*sA;
    const size_t gb0 = (size_t)(n0 + qa*16 + rL)*sB + kq*8;
    const size_t gb1 = gb0 + (size_t)16*sB;

    const int NT = K >> 5;
    bf16x8 av[8], bv[4];

#define STAGE_A(tile) { const size_t k0=(size_t)(tile)*32; \
    u16* sb = lds + ((tile)&3)*16384; \
    gl16(A + ga0 + k0, sb + qa*512); \
    gl16(A + ga1 + k0, sb + qa*512 + 512); }
#define STAGE_B(tile) { const size_t k0=(size_t)(tile)*32; \
    u16* sb = lds + ((tile)&3)*16384; \
    gl16(B + gb0 + k0, sb + 8192 + qa*512); \
    gl16(B + gb1 + k0, sb + 8192 + qa*512 + 512); }

#define FEN   __builtin_amdgcn_sched_barrier(0)
#define BARR  __builtin_amdgcn_s_barrier()
#define VMW(n) asm volatile("s_waitcnt vmcnt(" #n ")")
#define NOWAIT ((void)0)

#define PH0(tile, DOSTAGE) { \
    const u16* sb = lds + ((tile)&3)*16384; \
    _Pragma("unroll") \
    for (int i = 0; i < 4; ++i) av[i] = *(const bf16x8*)&sb[(ia0+i)*512 + L*8]; \
    _Pragma("unroll") \
    for (int j = 0; j < 4; ++j) bv[j] = *(const bf16x8*)&sb[8192 + (jb0+j)*512 + L*8]; \
    if (DOSTAGE) STAGE_A((tile)+3); \
    FEN; BARR; FEN; \
    __builtin_amdgcn_s_setprio(1); \
    _Pragma("unroll") \
    for (int i = 0; i < 4; ++i) \
        _Pragma("unroll") \
        for (int j = 0; j < 4; ++j) \
            acc[i][j] = __builtin_amdgcn_mfma_f32_16x16x32_bf16(av[i], bv[j], acc[i][j], 0,0,0); \
    __builtin_amdgcn_s_setprio(0); \
    FEN; BARR; }

#define PH1(tile, DOSTAGE, WAIT) { \
    const u16* sb = lds + ((tile)&3)*16384; \
    _Pragma("unroll") \
    for (int i = 0; i < 4; ++i) av[4+i] = *(const bf16x8*)&sb[(ia0+4+i)*512 + L*8]; \
    if (DOSTAGE) STAGE_B((tile)+3); \
    FEN; BARR; FEN; \
    __builtin_amdgcn_s_setprio(1); \
    _Pragma("unroll") \
    for (int i = 0; i < 4; ++i) \
        _Pragma("unroll") \
        for (int j = 0; j < 4; ++j) \
            acc[4+i][j] = __builtin_amdgcn_mfma_f32_16x16x32_bf16(av[4+i], bv[j], acc[4+i][j], 0,0,0); \
    __builtin_amdgcn_s_setprio(0); \
    FEN; WAIT; FEN; BARR; }

    // prologue: stage tiles 0,1,2 (12 loads/wave); vmcnt(8) completes tile 0
    STAGE_A(0); STAGE_B(0);
    STAGE_A(1); STAGE_B(1);
    STAGE_A(2); STAGE_B(2);
    FEN; VMW(8); FEN; BARR;

    for (int tt = 0; tt < NT-3; ++tt) {
        PH0(tt, 1);
        PH1(tt, 1, VMW(8));
    }
    PH0(NT-3, 0); PH1(NT-3, 0, VMW(4));
    PH0(NT-2, 0); PH1(NT-2, 0, VMW(0));
    PH0(NT-1, 0); PH1(NT-1, 0, NOWAIT);

#undef STAGE_A
#undef STAGE_B
#undef PH0
#undef PH1
#undef FEN
#undef BARR
#undef VMW
#undef NOWAIT
}

// ---------------------------------------------------------------------------
// elementwise: fp32 -> bf16
// ---------------------------------------------------------------------------
__global__ __launch_bounds__(256)
void cvt_bf16(const float* __restrict__ x, u16* __restrict__ y) {
    size_t i = ((size_t)blockIdx.x*256 + threadIdx.x)*4;
    float4 v = *(const float4*)&x[i];
    ushort4 h;
    h.x = f2bf(v.x); h.y = f2bf(v.y); h.z = f2bf(v.z); h.w = f2bf(v.w);
    *(ushort4*)&y[i] = h;
}

// ---------------------------------------------------------------------------
// QKV GEMM: A = Xbf, B = Wbf. Epilogue:
//   Q region: pre-scaled by 1/32, bf16, row-major  (pair-packed u32 stores)
//   K region: bf16, row-major                      (pair-packed u32 stores)
//   V region: bf16, transposed [b][d][s]           (ushort4 stores)
// XCD swizzle: nwg=768, cpx=96. chunk c = 8 m-rows x all 12 n-cols
// (A-panels 4MB resident in the XCD's L2; W shared via LLC).
// ---------------------------------------------------------------------------
__global__ __launch_bounds__(512,2)
void gemm_qkv(const u16* __restrict__ Xbf, const u16* __restrict__ Wbf,
              const float* __restrict__ bias,
              u16* __restrict__ Qh, u16* __restrict__ Kh,
              u16* __restrict__ Vth)
{
    __shared__ __align__(16) u16 lds[65536];   // 128 KB ring
    f32x4 acc[8][4];
    #pragma unroll
    for (int i=0;i<8;++i)
        #pragma unroll
        for (int j=0;j<4;++j) acc[i][j] = (f32x4){0.f,0.f,0.f,0.f};

    const int F = blockIdx.y*12 + blockIdx.x;   // gx=12, x-fastest
    const int c = F & 7, s = F >> 3;            // XCD chunk / slot
    const int mrow = c*8 + (s & 7);             // [0,64)
    const int ncol = s >> 3;                    // [0,12)
    const int m0 = mrow*256, n0 = ncol*256;
    gemm256(Xbf, DIM, Wbf, DIM, DIM, m0, n0, lds, acc);

    const int t = threadIdx.x, w = t>>6, L = t&63;
    const int wm = 128*(w>>2), wn = 64*(w&3);
    const int cl = L&15, rq = (L>>4)*4;
    const int region = n0 >> 10;           // whole 256-block in one region
    const float qscale = 0.03125f;

    if (region < 2) {
        u16* Dst = region ? Kh : Qh;
        const float fs = region ? 1.0f : qscale;
        #pragma unroll
        for (int j = 0; j < 4; ++j) {
            float bc = bias[n0 + wn + j*16 + cl];
            #pragma unroll
            for (int i = 0; i < 8; ++i)
                #pragma unroll
                for (int r = 0; r < 4; ++r)
                    acc[i][j][r] = (acc[i][j][r] + bc)*fs;
        }
        const int d0 = (n0 & 1023) + wn;
        #pragma unroll
        for (int p = 0; p < 2; ++p) {
            const int nt0 = 2*p, nt1 = 2*p+1;
            #pragma unroll
            for (int i = 0; i < 8; ++i) {
                int row0 = m0 + wm + i*16 + rq;
                int bi = row0 >> 12, s0 = row0 & (SEQ-1);
                #pragma unroll
                for (int r = 0; r < 4; ++r) {
                    float v0 = acc[i][nt0][r], v1 = acc[i][nt1][r];
                    float x0 = __shfl_xor(v0, 1, 64);
                    float x1 = __shfl_xor(v1, 1, 64);
                    unsigned wv; int colb;
                    if ((cl & 1) == 0) {
                        wv   = (unsigned)f2bf(v0) | ((unsigned)f2bf(x0) << 16);
                        colb = nt0*16 + cl;
                    } else {
                        wv   = (unsigned)f2bf(x1) | ((unsigned)f2bf(v1) << 16);
                        colb = nt1*16 + (cl-1);
                    }
                    size_t idx = ((size_t)bi*SEQ + s0 + r)*DIM + d0 + colb;
                    *(unsigned*)&Dst[idx] = wv;
                }
            }
        }
    } else {
        #pragma unroll
        for (int j = 0; j < 4; ++j) {
            int col = n0 + wn + j*16 + cl;
            float bc = bias[col];
            int d = col & (DIM-1);
            #pragma unroll
            for (int i = 0; i < 8; ++i) {
                int row0 = m0 + wm + i*16 + rq;
                int bi = row0 >> 12, s0 = row0 & (SEQ-1);
                ushort4 hv;
                hv.x = f2bf(acc[i][j][0] + bc);
                hv.y = f2bf(acc[i][j][1] + bc);
                hv.z = f2bf(acc[i][j][2] + bc);
                hv.w = f2bf(acc[i][j][3] + bc);
                size_t base = ((size_t)bi*DIM + d)*SEQ + s0;
                *(ushort4*)&Vth[base] = hv;
            }
        }
    }
}

// ---------------------------------------------------------------------------
// Scores, all batches: S_b = Qscaled_b @ K_b^T -> bf16, pair-packed stores.
// XCD swizzle: nwg=1024, cpx=128. chunk c = half-batch (bz=c>>1, 8 m-rows);
// within chunk 4 super-tiles of 4m x 8n (32 blocks = the XCD's concurrent
// set -> 4 A-panels + 8 B-panels ~ 6MB working set, mostly L2-resident).
// ---------------------------------------------------------------------------
__global__ __launch_bounds__(512,2)
void gemm_scores(const u16* __restrict__ Qh, const u16* __restrict__ Kh,
                 u16* __restrict__ S0, u16* __restrict__ S1,
                 u16* __restrict__ S2, u16* __restrict__ S3)
{
    __shared__ __align__(16) u16 lds[65536];
    f32x4 acc[8][4];
    #pragma unroll
    for (int i=0;i<8;++i)
        #pragma unroll
        for (int j=0;j<4;++j) acc[i][j] = (f32x4){0.f,0.f,0.f,0.f};

    const int F = (blockIdx.z*16 + blockIdx.y)*16 + blockIdx.x;
    const int c = F & 7, s = F >> 3;           // XCD chunk / slot (cpx=128)
    const int st = s >> 5, v = s & 31;         // super-tile, within
    const int bz   = c >> 1;
    const int mrow = (c&1)*8 + (st>>1)*4 + (v>>3);   // [0,16)
    const int ncol = (st&1)*8 + (v&7);               // [0,16)
    const size_t qo = (size_t)bz*SEQ*DIM;
    const int m0 = mrow*256, n0 = ncol*256;
    gemm256(Qh + qo, DIM, Kh + qo, DIM, DIM, m0, n0, lds, acc);

    u16* Sb = (bz == 0) ? S0 : (bz == 1) ? S1 : (bz == 2) ? S2 : S3;
    const int t = threadIdx.x, w = t>>6, L = t&63;
    const int wm = 128*(w>>2), wn = 64*(w&3);
    const int cl = L&15, rq = (L>>4)*4;
    #pragma unroll
    for (int p = 0; p < 2; ++p) {
        const int nt0 = 2*p, nt1 = 2*p+1;
        #pragma unroll
        for (int i = 0; i < 8; ++i) {
            int row0 = m0 + wm + i*16 + rq;
            #pragma unroll
            for (int r = 0; r < 4; ++r) {
                float v0 = acc[i][nt0][r], v1 = acc[i][nt1][r];
                float x0 = __shfl_xor(v0, 1, 64);
                float x1 = __shfl_xor(v1, 1, 64);
                unsigned wv; int colb;
                if ((cl & 1) == 0) {
                    wv   = (unsigned)f2bf(v0) | ((unsigned)f2bf(x0) << 16);
                    colb = nt0*16 + cl;
                } else {
                    wv   = (unsigned)f2bf(x1) | ((unsigned)f2bf(v1) << 16);
                    colb = nt1*16 + (cl-1);
                }
                *(unsigned*)&Sb[(size_t)(row0 + r)*SEQ + n0 + wn + colb] = wv;
            }
        }
    }
}

// ---------------------------------------------------------------------------
// Row softmax over bf16 S (pre-scaled scores), P bf16 in place. 16384 rows.
// ---------------------------------------------------------------------------
__global__ __launch_bounds__(256)
void softmax_pack(u16* __restrict__ S0, u16* __restrict__ S1,
                  u16* __restrict__ S2, u16* __restrict__ S3)
{
    __shared__ float red[4];
    const int t = threadIdx.x, L = t & 63, w = t >> 6;
    const int gr = blockIdx.x, bz = gr >> 12, rr = gr & (SEQ-1);
    u16* Sb = (bz == 0) ? S0 : (bz == 1) ? S1 : (bz == 2) ? S2 : S3;
    u16* row = Sb + (size_t)rr*SEQ;

    float v[16];
    float m = -1e30f;
    #pragma unroll
    for (int j = 0; j < 2; ++j) {
        ushort4 x0 = *(const ushort4*)&row[t*8 + j*2048];
        ushort4 x1 = *(const ushort4*)&row[t*8 + j*2048 + 4];
        union { unsigned u; float f; } c;
        c.u = (unsigned)x0.x << 16; v[8*j+0] = c.f;
        c.u = (unsigned)x0.y << 16; v[8*j+1] = c.f;
        c.u = (unsigned)x0.z << 16; v[8*j+2] = c.f;
        c.u = (unsigned)x0.w << 16; v[8*j+3] = c.f;
        c.u = (unsigned)x1.x << 16; v[8*j+4] = c.f;
        c.u = (unsigned)x1.y << 16; v[8*j+5] = c.f;
        c.u = (unsigned)x1.z << 16; v[8*j+6] = c.f;
        c.u = (unsigned)x1.w << 16; v[8*j+7] = c.f;
    }
    #pragma unroll
    for (int i = 0; i < 16; ++i) m = fmaxf(m, v[i]);
    #pragma unroll
    for (int off = 32; off; off >>= 1) m = fmaxf(m, __shfl_xor(m, off, 64));
    if (L == 0) red[w] = m;
    __syncthreads();
    m = fmaxf(fmaxf(red[0],red[1]), fmaxf(red[2],red[3]));

    float s = 0.f;
    #pragma unroll
    for (int i = 0; i < 16; ++i) { v[i] = __expf(v[i] - m); s += v[i]; }
    #pragma unroll
    for (int off = 32; off; off >>= 1) s += __shfl_xor(s, off, 64);
    __syncthreads();
    if (L == 0) red[w] = s;
    __syncthreads();
    s = red[0]+red[1]+red[2]+red[3];
    const float inv = 1.0f / s;

    #pragma unroll
    for (int j = 0; j < 2; ++j) {
        ushort4 h0, h1;
        h0.x = f2bf(v[8*j+0]*inv); h0.y = f2bf(v[8*j+1]*inv);
        h0.z = f2bf(v[8*j+2]*inv); h0.w = f2bf(v[8*j+3]*inv);
        h1.x = f2bf(v[8*j+4]*inv); h1.y = f2bf(v[8*j+5]*inv);
        h1.z = f2bf(v[8*j+6]*inv); h1.w = f2bf(v[8*j+7]*inv);
        *(ushort4*)&row[t*8 + j*2048]     = h0;
        *(ushort4*)&row[t*8 + j*2048 + 4] = h1;
    }
}

// ---------------------------------------------------------------------------
// PV, all batches: O_b = P_b @ Vt_b^T -> fp32 (scalar stores = full lines)
// XCD swizzle: nwg=256, cpx=32. chunk c = half-batch (8m x 4n); per-K-step
// the XCD's 32 blocks share 12 panel k-slices (~192KB) -> L2-hot.
// ---------------------------------------------------------------------------
__global__ __launch_bounds__(512,2)
void gemm_pv(const u16* __restrict__ P0, const u16* __restrict__ P1,
             const u16* __restrict__ P2, const u16* __restrict__ P3,
             const u16* __restrict__ Vth,
             float* __restrict__ O0, float* __restrict__ O1,
             float* __restrict__ O2, float* __restrict__ O3)
{
    __shared__ __align__(16) u16 lds[65536];
    f32x4 acc[8][4];
    #pragma unroll
    for (int i=0;i<8;++i)
        #pragma unroll
        for (int j=0;j<4;++j) acc[i][j] = (f32x4){0.f,0.f,0.f,0.f};

    const int F = (blockIdx.z*16 + blockIdx.y)*4 + blockIdx.x;
    const int c = F & 7, s = F >> 3;           // XCD chunk / slot (cpx=32)
    const int bz   = c >> 1;
    const int mrow = (c&1)*8 + (s>>2);         // [0,16)
    const int ncol = s & 3;                    // [0,4)
    const u16* Pb = (bz == 0) ? P0 : (bz == 1) ? P1 : (bz == 2) ? P2 : P3;
    float*     Ob = (bz == 0) ? O0 : (bz == 1) ? O1 : (bz == 2) ? O2 : O3;
    const int m0 = mrow*256, n0 = ncol*256;
    gemm256(Pb, SEQ, Vth + (size_t)bz*DIM*SEQ, SEQ, SEQ, m0, n0, lds, acc);

    const int t = threadIdx.x, w = t>>6, L = t&63;
    const int wm = 128*(w>>2), wn = 64*(w&3);
    const int cl = L&15, rq = (L>>4)*4;
    #pragma unroll
    for (int j = 0; j < 4; ++j) {
        int col = n0 + wn + j*16 + cl;
        #pragma unroll
        for (int i = 0; i < 8; ++i) {
            int row0 = m0 + wm + i*16 + rq;
            #pragma unroll
            for (int r = 0; r < 4; ++r)
                Ob[(size_t)(row0 + r)*DIM + col] = acc[i][j][r];
        }
    }
}

// ---------------------------------------------------------------------------
// linear copy (float4), for O2/O3 parked in ws -> d_out second half
// ---------------------------------------------------------------------------
__global__ __launch_bounds__(256)
void copy_out(const float* __restrict__ src, float* __restrict__ dst)
{
    size_t i = ((size_t)blockIdx.x*256 + threadIdx.x)*4;
    *(float4*)&dst[i] = *(const float4*)&src[i];
}

// ---------------------------------------------------------------------------
extern "C" void kernel_launch(void* const* d_in, const int* in_sizes, int n_in,
                              void* d_out, int out_size, void* d_ws, size_t ws_size,
                              hipStream_t stream) {
    const float* X    = (const float*)d_in[0];
    const float* W    = (const float*)d_in[1];
    const float* bias = (const float*)d_in[2];
    float* out = (float*)d_out;

    const size_t MB = (size_t)1 << 20;
    if (ws_size < 192*MB) return;
    char* ws = (char*)d_ws;
    char* wo = (char*)d_out;
    // ws: Qh[0,32) Kh[32,64) Vth[64,96) S0[96,128) S1[128,160) S2[160,192)
    u16* Qh  = (u16*)ws;
    u16* Kh  = (u16*)(ws + 32*MB);
    u16* Vth = (u16*)(ws + 64*MB);
    u16* S0  = (u16*)(ws + 96*MB);
    u16* S1  = (u16*)(ws + 128*MB);
    u16* S2  = (u16*)(ws + 160*MB);
    // d_out during prologue: Xbf[0,32) Wbf[32,38); during attention: S3[32,64)
    u16* Xbf = (u16*)wo;
    u16* Wbf = (u16*)(wo + 32*MB);
    u16* S3  = (u16*)(wo + 32*MB);
    // pv outputs: O0,O1 -> d_out[0,32); O2,O3 -> dead Qh/Kh-front ws[0,32)
    float* O0 = (float*)wo;
    float* O1 = (float*)(wo + 16*MB);
    float* O2 = (float*)ws;
    float* O3 = (float*)(ws + 16*MB);

    cvt_bf16<<<MTOT*DIM/1024, 256, 0, stream>>>(X, Xbf);
    cvt_bf16<<<E3*DIM/1024,   256, 0, stream>>>(W, Wbf);

    gemm_qkv<<<dim3(E3/256, MTOT/256), 512, 0, stream>>>(
        Xbf, Wbf, bias, Qh, Kh, Vth);

    gemm_scores<<<dim3(SEQ/256, SEQ/256, BATCH), 512, 0, stream>>>(
        Qh, Kh, S0, S1, S2, S3);

    softmax_pack<<<MTOT, 256, 0, stream>>>(S0, S1, S2, S3);

    gemm_pv<<<dim3(DIM/256, SEQ/256, BATCH), 512, 0, stream>>>(
        S0, S1, S2, S3, Vth, O0, O1, O2, O3);

    // O2,O3 (32 MB in ws) -> d_out[32,64)
    copy_out<<<(32*MB/sizeof(float))/1024, 256, 0, stream>>>(
        (const float*)ws, out + 8*MB);   // 8M floats = 32 MB offset
}

// Round 7
// 561.931 us; speedup vs baseline: 1.0952x; 1.0342x over previous
//
#include <hip/hip_runtime.h>
#include <cstdint>

typedef unsigned short u16;
typedef __attribute__((ext_vector_type(8))) short bf16x8;
typedef __attribute__((ext_vector_type(4))) float f32x4;

#define DIM   1024
#define BATCH 4
#define SEQ   4096
#define E3    3072
#define MTOT  (BATCH*SEQ)   // 16384

// ---------- bf16 helpers (RNE) ----------
__device__ __forceinline__ u16 f2bf(float x) {
    union { float f; unsigned u; } v; v.f = x;
    unsigned r = v.u + 0x7FFFu + ((v.u >> 16) & 1u);
    return (u16)(r >> 16);
}

// ---------- async global->LDS 16B ----------
__device__ __forceinline__ void gl16(const void* g, void* l) {
    __builtin_amdgcn_global_load_lds(
        (const __attribute__((address_space(1))) void*)g,
        (__attribute__((address_space(3))) void*)l, 16, 0, 0);
}

// ---------------------------------------------------------------------------
// GEMM mainloop: C[256x256] += A * B^T, both bf16 k-major, K mult of 64,
// K/64 >= 2. 512 thr = 8 waves (2m x 4n); per-wave 128x64 -> acc[8][4].
//
// ROUND-7 = ROUND-6 RESUBMIT (bench died at the harness level, no verdict;
// kernel re-audited: barriers uniform, vmcnt waits always satisfiable,
// addresses in-bounds, ring hazard 1+ barrier separated -> no hang vector).
//
// m201 cadence theory: rounds 1-5 all shared (a) 4 barrier-pairs/K-32 and
// (b) one whole-tile vmcnt publish point -> whole-CU convoy once per tile
// (m233: stage+vmcnt+bar = 72% of a 2-phase loop's time). This version:
//
//  BK=64, LDS = 2 x 64KB K-step buffers (A 32KB: frag(m,ks)=(m*2+ks)*1KB;
//  B 32KB at +32KB: frag(n,ks)). Fragment-identity chunks (lane L holds
//  row L&15, k-span (L>>4)*8) -> linear ds_read_b128, 0 bank conflicts,
//  matches global_load_lds linear dest.
//
//  4 phases per K-step t = quadrant (mh, ks): 16 MFMA each; reads 8/4/8/4
//  (bv(ks) read at mh=0, reused at mh=1). One stage UNIT per phase into
//  buf[(t+1)&1]: ph1->A-u0, ph2->B-u0, ph3->A-u1, ph4->B-u1 (2 gl16/thr).
//
//  JIT counted waits (never a whole-tile drain): before ph1/ph2/ph3 a
//  uniform vmcnt(4) -- allows the 4 newest loads (later units) in flight,
//  completes exactly the unit(s) this phase reads. ph4 reads only data
//  published at ph2/ph3 -> no wait, NO BARRIER. 3 barriers per K-64.
//
//  Race audit: stage of unit U(t+1) at phase p overwrites U(t-1), whose
//  last readers completed their ds_reads before their own iter-(t-1) MFMAs
//  (in-order lgkm + register consumption), hence before arriving at phase
//  p's barrier; the stage issues after that barrier. Stages always target
//  the opposite buffer from all reads in the same barrier window; ph4's
//  stage (B slots 2n+1) is disjoint from ph1's reads (slots 2n).
//  Tail iter: no stages; waits peel 4 -> 2 -> 0.
// ---------------------------------------------------------------------------
__device__ __forceinline__ void gemm256(
    const u16* __restrict__ A, int sA,
    const u16* __restrict__ B, int sB,
    int K, int m0, int n0,
    u16* lds, f32x4 acc[8][4])
{
    const int tid = threadIdx.x;
    const int w   = tid >> 6, L = tid & 63;
    const int rL  = L & 15, kq = L >> 4;
    const int wg8 = (w>>2)*8;      // wave-group A-frag base (m)
    const int jb4 = 4*(w&3);       // wave B-frag base (n)

    // stage assignments: A-unit(mh): wave w stages frag m = wg8 + mh*4 + (w&3),
    // both ks (2 gl16). B-unit(ks): wave w stages frags n = 2w, 2w+1 at ks.
    const int mA = wg8 + (w&3);
    const size_t gA  = (size_t)(m0 + mA*16 + rL)*sA + kq*8;   // +mh*64*sA +tn*64 +ks*32
    const size_t gAm = (size_t)64*sA;
    const size_t gB0 = (size_t)(n0 + (2*w)*16 + rL)*sB + kq*8; // +tn*64 +ks*32
    const size_t gB1 = gB0 + (size_t)16*sB;

    const int ldsA  = (mA*2)*512 + L*8;            // +mh*4096 +ks*512 (u16)
    const int ldsB0 = 16384 + (2*w*2)*512 + L*8;   // +ks*512
    const int ldsB1 = 16384 + ((2*w+1)*2)*512 + L*8;

    const int NT = K >> 6;
    bf16x8 av[4], bv[4];

#define FEN    __builtin_amdgcn_sched_barrier(0)
#define BARR   __builtin_amdgcn_s_barrier()
#define VMW(n) asm volatile("s_waitcnt vmcnt(" #n ")")

#define SAU(mh, tn) { u16* bn = lds + (((tn)&1)<<15); \
    const size_t g = gA + (size_t)(mh)*gAm + (size_t)(tn)*64; \
    gl16(A + g,      bn + ldsA + (mh)*4096); \
    gl16(A + g + 32, bn + ldsA + (mh)*4096 + 512); }

#define SBU(ks, tn) { u16* bn = lds + (((tn)&1)<<15); \
    const size_t g = (size_t)(tn)*64 + (size_t)(ks)*32; \
    gl16(B + gB0 + g, bn + ldsB0 + (ks)*512); \
    gl16(B + gB1 + g, bn + ldsB1 + (ks)*512); }

#define RD(mh, ks, tcur) { const u16* bc = lds + (((tcur)&1)<<15); \
    _Pragma("unroll") \
    for (int i = 0; i < 4; ++i) \
        av[i] = *(const bf16x8*)&bc[((wg8+(mh)*4+i)*2+(ks))*512 + L*8]; \
    if ((mh) == 0) { \
        _Pragma("unroll") \
        for (int j = 0; j < 4; ++j) \
            bv[j] = *(const bf16x8*)&bc[16384 + ((jb4+j)*2+(ks))*512 + L*8]; } }

#define MM(mh) { \
    __builtin_amdgcn_s_setprio(1); \
    _Pragma("unroll") \
    for (int i = 0; i < 4; ++i) \
        _Pragma("unroll") \
        for (int j = 0; j < 4; ++j) \
            acc[(mh)*4+i][j] = __builtin_amdgcn_mfma_f32_16x16x32_bf16(av[i], bv[j], acc[(mh)*4+i][j], 0,0,0); \
    __builtin_amdgcn_s_setprio(0); }

    // prologue: stage all 4 units of K-step 0 (8 loads/thread)
    SAU(0,0); SBU(0,0); SAU(1,0); SBU(1,0);

    for (int tt = 0; tt < NT-1; ++tt) {
        FEN; VMW(4); BARR; FEN;                 // publishes A-u0,B-u0 of tt
        RD(0,0,tt); FEN; SAU(0,tt+1); FEN; MM(0);
        FEN; VMW(4); BARR; FEN;                 // publishes A-u1 of tt
        RD(1,0,tt); FEN; SBU(0,tt+1); FEN; MM(1);
        FEN; VMW(4); BARR; FEN;                 // publishes B-u1 of tt
        RD(0,1,tt); FEN; SAU(1,tt+1); FEN; MM(0);
        FEN;                                    // ph4: all inputs published
        RD(1,1,tt); FEN; SBU(1,tt+1); FEN; MM(1);
    }
    {   const int tt = NT-1;                    // tail: no stages, drain 4->2->0
        FEN; VMW(4); BARR; FEN; RD(0,0,tt); FEN; MM(0);
        FEN; VMW(2); BARR; FEN; RD(1,0,tt); FEN; MM(1);
        FEN; VMW(0); BARR; FEN; RD(0,1,tt); FEN; MM(0);
        FEN;                    RD(1,1,tt); FEN; MM(1);
    }

#undef SAU
#undef SBU
#undef RD
#undef MM
#undef FEN
#undef BARR
#undef VMW
}

// ---------------------------------------------------------------------------
// elementwise: fp32 -> bf16
// ---------------------------------------------------------------------------
__global__ __launch_bounds__(256)
void cvt_bf16(const float* __restrict__ x, u16* __restrict__ y) {
    size_t i = ((size_t)blockIdx.x*256 + threadIdx.x)*4;
    float4 v = *(const float4*)&x[i];
    ushort4 h;
    h.x = f2bf(v.x); h.y = f2bf(v.y); h.z = f2bf(v.z); h.w = f2bf(v.w);
    *(ushort4*)&y[i] = h;
}

// ---------------------------------------------------------------------------
// QKV GEMM: A = Xbf, B = Wbf. Epilogue:
//   Q region: pre-scaled by 1/32, bf16, row-major  (pair-packed u32 stores)
//   K region: bf16, row-major                      (pair-packed u32 stores)
//   V region: bf16, transposed [b][d][s]           (ushort4 stores)
// XCD swizzle: nwg=768, cpx=96. chunk c = 8 m-rows x all 12 n-cols.
// ---------------------------------------------------------------------------
__global__ __launch_bounds__(512,2)
void gemm_qkv(const u16* __restrict__ Xbf, const u16* __restrict__ Wbf,
              const float* __restrict__ bias,
              u16* __restrict__ Qh, u16* __restrict__ Kh,
              u16* __restrict__ Vth)
{
    __shared__ __align__(16) u16 lds[65536];   // 2 x 64KB K-step buffers
    f32x4 acc[8][4];
    #pragma unroll
    for (int i=0;i<8;++i)
        #pragma unroll
        for (int j=0;j<4;++j) acc[i][j] = (f32x4){0.f,0.f,0.f,0.f};

    const int F = blockIdx.y*12 + blockIdx.x;   // gx=12, x-fastest
    const int c = F & 7, s = F >> 3;            // XCD chunk / slot
    const int mrow = c*8 + (s & 7);             // [0,64)
    const int ncol = s >> 3;                    // [0,12)
    const int m0 = mrow*256, n0 = ncol*256;
    gemm256(Xbf, DIM, Wbf, DIM, DIM, m0, n0, lds, acc);

    const int t = threadIdx.x, w = t>>6, L = t&63;
    const int wm = 128*(w>>2), wn = 64*(w&3);
    const int cl = L&15, rq = (L>>4)*4;
    const int region = n0 >> 10;           // whole 256-block in one region
    const float qscale = 0.03125f;

    if (region < 2) {
        u16* Dst = region ? Kh : Qh;
        const float fs = region ? 1.0f : qscale;
        #pragma unroll
        for (int j = 0; j < 4; ++j) {
            float bc = bias[n0 + wn + j*16 + cl];
            #pragma unroll
            for (int i = 0; i < 8; ++i)
                #pragma unroll
                for (int r = 0; r < 4; ++r)
                    acc[i][j][r] = (acc[i][j][r] + bc)*fs;
        }
        const int d0 = (n0 & 1023) + wn;
        #pragma unroll
        for (int p = 0; p < 2; ++p) {
            const int nt0 = 2*p, nt1 = 2*p+1;
            #pragma unroll
            for (int i = 0; i < 8; ++i) {
                int row0 = m0 + wm + i*16 + rq;
                int bi = row0 >> 12, s0 = row0 & (SEQ-1);
                #pragma unroll
                for (int r = 0; r < 4; ++r) {
                    float v0 = acc[i][nt0][r], v1 = acc[i][nt1][r];
                    float x0 = __shfl_xor(v0, 1, 64);
                    float x1 = __shfl_xor(v1, 1, 64);
                    unsigned wv; int colb;
                    if ((cl & 1) == 0) {
                        wv   = (unsigned)f2bf(v0) | ((unsigned)f2bf(x0) << 16);
                        colb = nt0*16 + cl;
                    } else {
                        wv   = (unsigned)f2bf(x1) | ((unsigned)f2bf(v1) << 16);
                        colb = nt1*16 + (cl-1);
                    }
                    size_t idx = ((size_t)bi*SEQ + s0 + r)*DIM + d0 + colb;
                    *(unsigned*)&Dst[idx] = wv;
                }
            }
        }
    } else {
        #pragma unroll
        for (int j = 0; j < 4; ++j) {
            int col = n0 + wn + j*16 + cl;
            float bc = bias[col];
            int d = col & (DIM-1);
            #pragma unroll
            for (int i = 0; i < 8; ++i) {
                int row0 = m0 + wm + i*16 + rq;
                int bi = row0 >> 12, s0 = row0 & (SEQ-1);
                ushort4 hv;
                hv.x = f2bf(acc[i][j][0] + bc);
                hv.y = f2bf(acc[i][j][1] + bc);
                hv.z = f2bf(acc[i][j][2] + bc);
                hv.w = f2bf(acc[i][j][3] + bc);
                size_t base = ((size_t)bi*DIM + d)*SEQ + s0;
                *(ushort4*)&Vth[base] = hv;
            }
        }
    }
}

// ---------------------------------------------------------------------------
// Scores, all batches: S_b = Qscaled_b @ K_b^T -> bf16, pair-packed stores.
// XCD swizzle: nwg=1024, cpx=128. chunk c = half-batch; 4 super-tiles 4m x 8n.
// ---------------------------------------------------------------------------
__global__ __launch_bounds__(512,2)
void gemm_scores(const u16* __restrict__ Qh, const u16* __restrict__ Kh,
                 u16* __restrict__ S0, u16* __restrict__ S1,
                 u16* __restrict__ S2, u16* __restrict__ S3)
{
    __shared__ __align__(16) u16 lds[65536];
    f32x4 acc[8][4];
    #pragma unroll
    for (int i=0;i<8;++i)
        #pragma unroll
        for (int j=0;j<4;++j) acc[i][j] = (f32x4){0.f,0.f,0.f,0.f};

    const int F = (blockIdx.z*16 + blockIdx.y)*16 + blockIdx.x;
    const int c = F & 7, s = F >> 3;           // XCD chunk / slot (cpx=128)
    const int st = s >> 5, v = s & 31;         // super-tile, within
    const int bz   = c >> 1;
    const int mrow = (c&1)*8 + (st>>1)*4 + (v>>3);   // [0,16)
    const int ncol = (st&1)*8 + (v&7);               // [0,16)
    const size_t qo = (size_t)bz*SEQ*DIM;
    const int m0 = mrow*256, n0 = ncol*256;
    gemm256(Qh + qo, DIM, Kh + qo, DIM, DIM, m0, n0, lds, acc);

    u16* Sb = (bz == 0) ? S0 : (bz == 1) ? S1 : (bz == 2) ? S2 : S3;
    const int t = threadIdx.x, w = t>>6, L = t&63;
    const int wm = 128*(w>>2), wn = 64*(w&3);
    const int cl = L&15, rq = (L>>4)*4;
    #pragma unroll
    for (int p = 0; p < 2; ++p) {
        const int nt0 = 2*p, nt1 = 2*p+1;
        #pragma unroll
        for (int i = 0; i < 8; ++i) {
            int row0 = m0 + wm + i*16 + rq;
            #pragma unroll
            for (int r = 0; r < 4; ++r) {
                float v0 = acc[i][nt0][r], v1 = acc[i][nt1][r];
                float x0 = __shfl_xor(v0, 1, 64);
                float x1 = __shfl_xor(v1, 1, 64);
                unsigned wv; int colb;
                if ((cl & 1) == 0) {
                    wv   = (unsigned)f2bf(v0) | ((unsigned)f2bf(x0) << 16);
                    colb = nt0*16 + cl;
                } else {
                    wv   = (unsigned)f2bf(x1) | ((unsigned)f2bf(v1) << 16);
                    colb = nt1*16 + (cl-1);
                }
                *(unsigned*)&Sb[(size_t)(row0 + r)*SEQ + n0 + wn + colb] = wv;
            }
        }
    }
}

// ---------------------------------------------------------------------------
// Row softmax over bf16 S (pre-scaled scores), P bf16 in place. 16384 rows.
// ---------------------------------------------------------------------------
__global__ __launch_bounds__(256)
void softmax_pack(u16* __restrict__ S0, u16* __restrict__ S1,
                  u16* __restrict__ S2, u16* __restrict__ S3)
{
    __shared__ float red[4];
    const int t = threadIdx.x, L = t & 63, w = t >> 6;
    const int gr = blockIdx.x, bz = gr >> 12, rr = gr & (SEQ-1);
    u16* Sb = (bz == 0) ? S0 : (bz == 1) ? S1 : (bz == 2) ? S2 : S3;
    u16* row = Sb + (size_t)rr*SEQ;

    float v[16];
    float m = -1e30f;
    #pragma unroll
    for (int j = 0; j < 2; ++j) {
        ushort4 x0 = *(const ushort4*)&row[t*8 + j*2048];
        ushort4 x1 = *(const ushort4*)&row[t*8 + j*2048 + 4];
        union { unsigned u; float f; } c;
        c.u = (unsigned)x0.x << 16; v[8*j+0] = c.f;
        c.u = (unsigned)x0.y << 16; v[8*j+1] = c.f;
        c.u = (unsigned)x0.z << 16; v[8*j+2] = c.f;
        c.u = (unsigned)x0.w << 16; v[8*j+3] = c.f;
        c.u = (unsigned)x1.x << 16; v[8*j+4] = c.f;
        c.u = (unsigned)x1.y << 16; v[8*j+5] = c.f;
        c.u = (unsigned)x1.z << 16; v[8*j+6] = c.f;
        c.u = (unsigned)x1.w << 16; v[8*j+7] = c.f;
    }
    #pragma unroll
    for (int i = 0; i < 16; ++i) m = fmaxf(m, v[i]);
    #pragma unroll
    for (int off = 32; off; off >>= 1) m = fmaxf(m, __shfl_xor(m, off, 64));
    if (L == 0) red[w] = m;
    __syncthreads();
    m = fmaxf(fmaxf(red[0],red[1]), fmaxf(red[2],red[3]));

    float s = 0.f;
    #pragma unroll
    for (int i = 0; i < 16; ++i) { v[i] = __expf(v[i] - m); s += v[i]; }
    #pragma unroll
    for (int off = 32; off; off >>= 1) s += __shfl_xor(s, off, 64);
    __syncthreads();
    if (L == 0) red[w] = s;
    __syncthreads();
    s = red[0]+red[1]+red[2]+red[3];
    const float inv = 1.0f / s;

    #pragma unroll
    for (int j = 0; j < 2; ++j) {
        ushort4 h0, h1;
        h0.x = f2bf(v[8*j+0]*inv); h0.y = f2bf(v[8*j+1]*inv);
        h0.z = f2bf(v[8*j+2]*inv); h0.w = f2bf(v[8*j+3]*inv);
        h1.x = f2bf(v[8*j+4]*inv); h1.y = f2bf(v[8*j+5]*inv);
        h1.z = f2bf(v[8*j+6]*inv); h1.w = f2bf(v[8*j+7]*inv);
        *(ushort4*)&row[t*8 + j*2048]     = h0;
        *(ushort4*)&row[t*8 + j*2048 + 4] = h1;
    }
}

// ---------------------------------------------------------------------------
// PV, all batches: O_b = P_b @ Vt_b^T -> fp32 (scalar stores = full lines)
// XCD swizzle: nwg=256, cpx=32. chunk c = half-batch (8m x 4n).
// ---------------------------------------------------------------------------
__global__ __launch_bounds__(512,2)
void gemm_pv(const u16* __restrict__ P0, const u16* __restrict__ P1,
             const u16* __restrict__ P2, const u16* __restrict__ P3,
             const u16* __restrict__ Vth,
             float* __restrict__ O0, float* __restrict__ O1,
             float* __restrict__ O2, float* __restrict__ O3)
{
    __shared__ __align__(16) u16 lds[65536];
    f32x4 acc[8][4];
    #pragma unroll
    for (int i=0;i<8;++i)
        #pragma unroll
        for (int j=0;j<4;++j) acc[i][j] = (f32x4){0.f,0.f,0.f,0.f};

    const int F = (blockIdx.z*16 + blockIdx.y)*4 + blockIdx.x;
    const int c = F & 7, s = F >> 3;           // XCD chunk / slot (cpx=32)
    const int bz   = c >> 1;
    const int mrow = (c&1)*8 + (s>>2);         // [0,16)
    const int ncol = s & 3;                    // [0,4)
    const u16* Pb = (bz == 0) ? P0 : (bz == 1) ? P1 : (bz == 2) ? P2 : P3;
    float*     Ob = (bz == 0) ? O0 : (bz == 1) ? O1 : (bz == 2) ? O2 : O3;
    const int m0 = mrow*256, n0 = ncol*256;
    gemm256(Pb, SEQ, Vth + (size_t)bz*DIM*SEQ, SEQ, SEQ, m0, n0, lds, acc);

    const int t = threadIdx.x, w = t>>6, L = t&63;
    const int wm = 128*(w>>2), wn = 64*(w&3);
    const int cl = L&15, rq = (L>>4)*4;
    #pragma unroll
    for (int j = 0; j < 4; ++j) {
        int col = n0 + wn + j*16 + cl;
        #pragma unroll
        for (int i = 0; i < 8; ++i) {
            int row0 = m0 + wm + i*16 + rq;
            #pragma unroll
            for (int r = 0; r < 4; ++r)
                Ob[(size_t)(row0 + r)*DIM + col] = acc[i][j][r];
        }
    }
}

// ---------------------------------------------------------------------------
// linear copy (float4), for O2/O3 parked in ws -> d_out second half
// ---------------------------------------------------------------------------
__global__ __launch_bounds__(256)
void copy_out(const float* __restrict__ src, float* __restrict__ dst)
{
    size_t i = ((size_t)blockIdx.x*256 + threadIdx.x)*4;
    *(float4*)&dst[i] = *(const float4*)&src[i];
}

// ---------------------------------------------------------------------------
extern "C" void kernel_launch(void* const* d_in, const int* in_sizes, int n_in,
                              void* d_out, int out_size, void* d_ws, size_t ws_size,
                              hipStream_t stream) {
    const float* X    = (const float*)d_in[0];
    const float* W    = (const float*)d_in[1];
    const float* bias = (const float*)d_in[2];
    float* out = (float*)d_out;

    const size_t MB = (size_t)1 << 20;
    if (ws_size < 192*MB) return;
    char* ws = (char*)d_ws;
    char* wo = (char*)d_out;
    // ws: Qh[0,32) Kh[32,64) Vth[64,96) S0[96,128) S1[128,160) S2[160,192)
    u16* Qh  = (u16*)ws;
    u16* Kh  = (u16*)(ws + 32*MB);
    u16* Vth = (u16*)(ws + 64*MB);
    u16* S0  = (u16*)(ws + 96*MB);
    u16* S1  = (u16*)(ws + 128*MB);
    u16* S2  = (u16*)(ws + 160*MB);
    // d_out during prologue: Xbf[0,32) Wbf[32,38); during attention: S3[32,64)
    u16* Xbf = (u16*)wo;
    u16* Wbf = (u16*)(wo + 32*MB);
    u16* S3  = (u16*)(wo + 32*MB);
    // pv outputs: O0,O1 -> d_out[0,32); O2,O3 -> dead Qh/Kh-front ws[0,32)
    float* O0 = (float*)wo;
    float* O1 = (float*)(wo + 16*MB);
    float* O2 = (float*)ws;
    float* O3 = (float*)(ws + 16*MB);

    cvt_bf16<<<MTOT*DIM/1024, 256, 0, stream>>>(X, Xbf);
    cvt_bf16<<<E3*DIM/1024,   256, 0, stream>>>(W, Wbf);

    gemm_qkv<<<dim3(E3/256, MTOT/256), 512, 0, stream>>>(
        Xbf, Wbf, bias, Qh, Kh, Vth);

    gemm_scores<<<dim3(SEQ/256, SEQ/256, BATCH), 512, 0, stream>>>(
        Qh, Kh, S0, S1, S2, S3);

    softmax_pack<<<MTOT, 256, 0, stream>>>(S0, S1, S2, S3);

    gemm_pv<<<dim3(DIM/256, SEQ/256, BATCH), 512, 0, stream>>>(
        S0, S1, S2, S3, Vth, O0, O1, O2, O3);

    // O2,O3 (32 MB in ws) -> d_out[32,64)
    copy_out<<<(32*MB/sizeof(float))/1024, 256, 0, stream>>>(
        (const float*)ws, out + 8*MB);   // 8M floats = 32 MB offset
}